// Round 10
// baseline (458.065 us; speedup 1.0000x reference)
//
#include <hip/hip_runtime.h>
#include <hip/hip_bf16.h>
#include <stdint.h>

typedef __attribute__((ext_vector_type(8))) short short8;
typedef __attribute__((ext_vector_type(4))) float floatx4;
typedef __attribute__((ext_vector_type(2))) unsigned int uint2v;

#define DEV static __device__ __forceinline__

DEV unsigned short f2bs(float f) {           // f32 -> bf16 bits, RNE
  union { float f; unsigned u; } v; v.f = f;
  unsigned u = v.u;
  u += 0x7fffu + ((u >> 16) & 1u);
  return (unsigned short)(u >> 16);
}
DEV float bs2f(unsigned short s) {
  union { unsigned u; float f; } v; v.u = ((unsigned)s) << 16;
  return v.f;
}
DEV unsigned pack2(float a, float b) {
  return (unsigned)f2bs(a) | ((unsigned)f2bs(b) << 16);
}

DEV void gload_lds16(const void* g, void* l) {
  __builtin_amdgcn_global_load_lds(
      (const __attribute__((address_space(1))) void*)g,
      (__attribute__((address_space(3))) void*)l, 16, 0, 0);
}

static constexpr int Hdim = 1024;
static constexpr int KDim = 512;
static constexpr int NH = 16;
static constexpr int HK = 32;
static constexpr int HV = 64;
static constexpr int Mtok = 4 * 8192;

// ---------- f32 -> bf16 convert (weights) ----------
__global__ __launch_bounds__(256) void k_cvt(const float4* __restrict__ in,
                                             uint2v* __restrict__ out, int n4) {
  int i = blockIdx.x * 256 + threadIdx.x;
  if (i >= n4) return;
  float4 v = in[i];
  uint2v o;
  o.x = pack2(v.x, v.y);
  o.y = pack2(v.z, v.w);
  out[i] = o;
}

// ---------- S -> S^T bf16:  St[b][h][v][k] = S[b][h][k][v] ----------
__global__ __launch_bounds__(256) void k_cvts(const float* __restrict__ S,
                                              unsigned short* __restrict__ St) {
  int i = blockIdx.x * 256 + threadIdx.x;      // over out idx, 4*16*64*32
  if (i >= 4 * NH * HV * HK) return;
  int k = i & 31, v = (i >> 5) & 63, bh = i >> 11;
  St[i] = f2bs(S[(size_t)(bh * HK + k) * HV + v]);
}

// ---------- rmsnorm(hidden) -> X bf16 ----------
__global__ __launch_bounds__(256) void k_rmsnorm(const float* __restrict__ hs,
                                                 const float* __restrict__ nw,
                                                 uint2v* __restrict__ X) {
  const int token = blockIdx.x;
  const int tid = threadIdx.x;
  float4 h = ((const float4*)(hs + (size_t)token * Hdim))[tid];
  float ss = h.x * h.x + h.y * h.y + h.z * h.z + h.w * h.w;
#pragma unroll
  for (int off = 32; off > 0; off >>= 1) ss += __shfl_down(ss, off, 64);
  __shared__ float red[4];
  const int lane = tid & 63, wid = tid >> 6;
  if (lane == 0) red[wid] = ss;
  __syncthreads();
  float tot = red[0] + red[1] + red[2] + red[3];
  float sc = rsqrtf(tot * (1.0f / Hdim) + 1e-5f);
  float4 w = ((const float4*)nw)[tid];
  uint2v o;
  o.x = pack2(h.x * sc * w.x, h.y * sc * w.y);
  o.y = pack2(h.z * sc * w.z, h.w * sc * w.w);
  X[(size_t)token * 256 + tid] = o;
}

// ---------- 128^2 / BK=64 GEMM core v5: hybrid staging ---------------------
// A (HBM-streamed): gload_lds into LDS, T2-swizzled, double-buffered (32 KB).
// B (L2-hot weights): global->register, double-buffered in regs; for fixed
// (kk,ni) a wave reads 16 rows x 64B contiguous -> full-line coalescing.
// 2-phase: issue A-stage(t+1)+B-load(t+1) BEFORE compute(t); one
// vmcnt(0)+barrier per K-step after compute. Ends with __syncthreads.
DEV void stageA(const unsigned short* __restrict__ Ag, const int K,
                const int k0, unsigned short* slot, const int tid) {
  char* dst = (char*)slot + tid * 16;
#pragma unroll
  for (int i = 0; i < 4; ++i)
    gload_lds16(Ag + (size_t)i * 32 * K + k0, dst + i * 4096);
}

DEV void loadB(const unsigned short* __restrict__ Bg, const int K,
               const int k0, short8 (&b)[2][4]) {
#pragma unroll
  for (int kk = 0; kk < 2; ++kk)
#pragma unroll
    for (int ni = 0; ni < 4; ++ni)
      b[kk][ni] = *(const short8*)&Bg[(size_t)ni * 16 * K + k0 + kk * 32];
}

DEV void computeA(const unsigned short* __restrict__ Asb,
                  const short8 (&b)[2][4], floatx4 (&acc)[4][4], const int wr,
                  const int frr, const int frk, const int aswz) {
#pragma unroll
  for (int kk = 0; kk < 2; ++kk) {
    short8 a[4];
#pragma unroll
    for (int mi = 0; mi < 4; ++mi)
      a[mi] = *(const short8*)
          &Asb[(wr * 64 + mi * 16 + frr) * 64 + ((kk * 32 + frk) ^ aswz)];
#pragma unroll
    for (int mi = 0; mi < 4; ++mi)
#pragma unroll
      for (int ni = 0; ni < 4; ++ni)
        acc[mi][ni] = __builtin_amdgcn_mfma_f32_16x16x32_bf16(
            a[mi], b[kk][ni], acc[mi][ni], 0, 0, 0);
  }
}

#define WAITSYNC()                                   \
  asm volatile("s_waitcnt vmcnt(0)" ::: "memory");   \
  __builtin_amdgcn_s_barrier();                      \
  asm volatile("" ::: "memory")

// LDS: 2 slots x 8192 shorts (32 KB total). K must be a multiple of 128.
DEV void gemm128h(const unsigned short* __restrict__ A,
                  const unsigned short* __restrict__ Bw, const int K,
                  const int m0, const int n0, unsigned short* LDS,
                  floatx4 (&acc)[4][4], const int tid) {
  const int lane = tid & 63;
  const int w = tid >> 6;
  const int wr = w >> 1, wc = w & 1;
  const int frr = lane & 15;
  const int frk = (lane >> 4) * 8;
  const int aswz = (frr & 7) * 8;
  const int r_a = tid >> 3;                         // 0..31
  const int c_src = ((tid & 7) ^ (r_a & 7)) * 8;    // pre-swizzled col
  const unsigned short* Ag = A + (size_t)(m0 + r_a) * K + c_src;
  const unsigned short* Bg = Bw + (size_t)(n0 + wc * 64 + frr) * K + frk;
  const int NT = K >> 6;                            // even (K%128==0)

  short8 b0[2][4], b1[2][4];
  // prologue: tile 0 -> slot0 + b0
  stageA(Ag, K, 0, LDS, tid);
  loadB(Bg, K, 0, b0);
  WAITSYNC();

  for (int t = 0; t < NT; t += 2) {
    // even step: compute slot0/b0; prefetch t+1 -> slot1/b1
    if (t + 1 < NT) {
      stageA(Ag, K, (t + 1) * 64, LDS + 8192, tid);
      loadB(Bg, K, (t + 1) * 64, b1);
    }
    computeA(LDS, b0, acc, wr, frr, frk, aswz);
    if (t + 1 < NT) {
      WAITSYNC();
    }
    // odd step: compute slot1/b1; prefetch t+2 -> slot0/b0
    if (t + 1 < NT) {
      if (t + 2 < NT) {
        stageA(Ag, K, (t + 2) * 64, LDS, tid);
        loadB(Bg, K, (t + 2) * 64, b0);
      }
      computeA(LDS + 8192, b1, acc, wr, frr, frk, aswz);
      if (t + 2 < NT) {
        WAITSYNC();
      }
    }
  }
  __syncthreads();
}

// ---------- fused gate+o:  out = sigmoid(X@gw^T) * (Ob@ow^T), f32 ----------
// 1D grid 2048; XCD-chunked, m-major within chunk (A-tile L2-resident).
__global__ __launch_bounds__(256, 2) void k_fused_go(
    const unsigned short* __restrict__ X, const unsigned short* __restrict__ Ob,
    const unsigned short* __restrict__ gwb,
    const unsigned short* __restrict__ owb, float* __restrict__ out) {
  __shared__ unsigned short LDS[2 * 128 * 64];   // 32 KB (2 A-slots)
  const int tid = threadIdx.x;
  const int lane = tid & 63;
  const int w = tid >> 6;
  const int wr = w >> 1, wc = w & 1;
  const int bid = blockIdx.x;               // nwg = 2048 (multiple of 8)
  const int v = (bid & 7) * 256 + (bid >> 3);
  const int m0 = (v >> 3) * 128;            // m-major within XCD chunk
  const int n0 = (v & 7) * 128;

  floatx4 acc[4][4];
#pragma unroll
  for (int i = 0; i < 4; ++i)
#pragma unroll
    for (int j = 0; j < 4; ++j) acc[i][j] = (floatx4){0.f, 0.f, 0.f, 0.f};

  // pass 1: gate
  gemm128h(X, gwb, Hdim, m0, n0, LDS, acc, tid);

  // sigmoid -> packed bf16 stash
  unsigned pg[4][4][2];
#pragma unroll
  for (int mi = 0; mi < 4; ++mi)
#pragma unroll
    for (int ni = 0; ni < 4; ++ni) {
      float s0 = 1.0f / (1.0f + __expf(-acc[mi][ni][0]));
      float s1 = 1.0f / (1.0f + __expf(-acc[mi][ni][1]));
      float s2 = 1.0f / (1.0f + __expf(-acc[mi][ni][2]));
      float s3 = 1.0f / (1.0f + __expf(-acc[mi][ni][3]));
      pg[mi][ni][0] = pack2(s0, s1);
      pg[mi][ni][1] = pack2(s2, s3);
      acc[mi][ni] = (floatx4){0.f, 0.f, 0.f, 0.f};
    }

  // pass 2: o-proj
  gemm128h(Ob, owb, Hdim, m0, n0, LDS, acc, tid);

  // epilogue: C/D layout col = lane&15, row = (lane>>4)*4 + r
  const int rb = (lane >> 4) * 4;
#pragma unroll
  for (int mi = 0; mi < 4; ++mi)
#pragma unroll
    for (int ni = 0; ni < 4; ++ni) {
      const int n = n0 + wc * 64 + ni * 16 + (lane & 15);
#pragma unroll
      for (int r = 0; r < 4; ++r) {
        const int m = m0 + wr * 64 + mi * 16 + rb + r;
        float g = bs2f((unsigned short)(pg[mi][ni][r >> 1] >> ((r & 1) * 16)));
        out[(size_t)m * Hdim + n] = g * acc[mi][ni][r];
      }
    }
}

// ---------- fused q-path: q=X@qw^T -> L2-normalize per head -> @S -> rmsnorm
// tile: 128 tokens x 128 q-dims = 4 full heads. Writes Ob bf16 directly.
__global__ __launch_bounds__(256, 2) void k_fused_q(
    const unsigned short* __restrict__ X, const unsigned short* __restrict__ qwb,
    const unsigned short* __restrict__ St, const float* __restrict__ vnw,
    unsigned short* __restrict__ Ob) {
  __shared__ unsigned short LD[128 * 128];  // 32 KB: GEMM dbuf, then q-tile
  const int tid = threadIdx.x;
  const int lane = tid & 63;
  const int w = tid >> 6;
  const int wr = w >> 1, wc = w & 1;
  const int bid = blockIdx.x;               // nwg = 1024
  const int v = (bid & 7) * 128 + (bid >> 3);
  const int m0 = (v >> 2) * 128;
  const int n0 = (v & 3) * 128;             // q-dim base; heads h0..h0+3
  const int h0 = n0 >> 5;
  const int batch = m0 >> 13;               // 8192 tokens per batch

  floatx4 acc[4][4];
#pragma unroll
  for (int i = 0; i < 4; ++i)
#pragma unroll
    for (int j = 0; j < 4; ++j) acc[i][j] = (floatx4){0.f, 0.f, 0.f, 0.f};

  gemm128h(X, qwb, Hdim, m0, n0, LD, acc, tid);

  // per-(row,head) L2 norm over 32 dims = 2 ni-frags x 16 lanes, then scale,
  // then store normalized q bf16 into swizzled LDS tile qt[m][c^((m&7)*8)].
  const int rb = (lane >> 4) * 4;
  const int frr = lane & 15;
#pragma unroll
  for (int mi = 0; mi < 4; ++mi)
#pragma unroll
    for (int p = 0; p < 2; ++p) {      // head-half: ni = 2p, 2p+1
#pragma unroll
      for (int r = 0; r < 4; ++r) {
        float v0 = acc[mi][2 * p][r], v1 = acc[mi][2 * p + 1][r];
        float ss = v0 * v0 + v1 * v1;
        ss += __shfl_xor(ss, 1, 64);
        ss += __shfl_xor(ss, 2, 64);
        ss += __shfl_xor(ss, 4, 64);
        ss += __shfl_xor(ss, 8, 64);
        const float inv = 1.0f / fmaxf(sqrtf(ss), 1e-12f);
        const int m = wr * 64 + mi * 16 + rb + r;
        const int c0 = wc * 64 + p * 32 + frr;
        const int sw = (m & 7) * 8;
        LD[m * 128 + (c0 ^ sw)] = f2bs(v0 * inv);
        LD[m * 128 + ((c0 + 16) ^ sw)] = f2bs(v1 * inv);
      }
    }
  __syncthreads();

  // contraction: per head hh, o[32w..32w+31][64] = qn[.,32] @ St[h]^T via MFMA
  // wave w owns token rows m = w*32 .. w*32+31.
  const int frk = (lane >> 4) * 8;   // k sub-range within K=32
  float wv[4];
#pragma unroll
  for (int ni = 0; ni < 4; ++ni) wv[ni] = vnw[ni * 16 + frr];

#pragma unroll
  for (int hh = 0; hh < 4; ++hh) {
    const unsigned short* Sp =
        St + (size_t)(batch * NH + h0 + hh) * (HV * HK);
    short8 bfr[4];
#pragma unroll
    for (int ni = 0; ni < 4; ++ni)
      bfr[ni] = *(const short8*)&Sp[(ni * 16 + frr) * HK + frk];
    floatx4 acc2[2][4];
#pragma unroll
    for (int i = 0; i < 2; ++i)
#pragma unroll
      for (int j = 0; j < 4; ++j) acc2[i][j] = (floatx4){0.f, 0.f, 0.f, 0.f};
    short8 af[2];
#pragma unroll
    for (int mi2 = 0; mi2 < 2; ++mi2) {
      const int m = w * 32 + mi2 * 16 + frr;
      af[mi2] = *(const short8*)&LD[m * 128 + ((hh * 32 + frk) ^ ((m & 7) * 8))];
    }
#pragma unroll
    for (int mi2 = 0; mi2 < 2; ++mi2)
#pragma unroll
      for (int ni = 0; ni < 4; ++ni)
        acc2[mi2][ni] = __builtin_amdgcn_mfma_f32_16x16x32_bf16(
            af[mi2], bfr[ni], acc2[mi2][ni], 0, 0, 0);

    // v-rmsnorm over 64 dims = 4 ni-frags x 16 lanes; write Ob bf16
#pragma unroll
    for (int mi2 = 0; mi2 < 2; ++mi2)
#pragma unroll
      for (int r = 0; r < 4; ++r) {
        float ss2 = 0.f;
#pragma unroll
        for (int ni = 0; ni < 4; ++ni) ss2 += acc2[mi2][ni][r] * acc2[mi2][ni][r];
        ss2 += __shfl_xor(ss2, 1, 64);
        ss2 += __shfl_xor(ss2, 2, 64);
        ss2 += __shfl_xor(ss2, 4, 64);
        ss2 += __shfl_xor(ss2, 8, 64);
        const float sc = rsqrtf(ss2 * (1.0f / HV) + 1e-5f);
        const int m = m0 + w * 32 + mi2 * 16 + rb + r;
        unsigned short* Op = Ob + (size_t)m * Hdim + (h0 + hh) * HV;
#pragma unroll
        for (int ni = 0; ni < 4; ++ni)
          Op[ni * 16 + frr] = f2bs(acc2[mi2][ni][r] * sc * wv[ni]);
      }
  }
}

extern "C" void kernel_launch(void* const* d_in, const int* in_sizes, int n_in,
                              void* d_out, int out_size, void* d_ws, size_t ws_size,
                              hipStream_t stream) {
  const float* hs = (const float*)d_in[0];
  const float* Srec = (const float*)d_in[1];
  const float* nw = (const float*)d_in[2];
  const float* qw = (const float*)d_in[3];
  const float* vnw = (const float*)d_in[4];
  const float* ow = (const float*)d_in[5];
  const float* gw = (const float*)d_in[6];

  char* ws = (char*)d_ws;
  unsigned short* X = (unsigned short*)(ws);                          // 64 MB bf16 [M,H]
  unsigned short* Ob = (unsigned short*)(ws + ((size_t)64 << 20));    // 64 MB bf16 [M,VD]
  unsigned short* qwb = (unsigned short*)(ws + ((size_t)128 << 20));  // 1 MB
  unsigned short* gwb = (unsigned short*)(ws + ((size_t)129 << 20));  // 2 MB
  unsigned short* owb = (unsigned short*)(ws + ((size_t)131 << 20));  // 2 MB
  unsigned short* Stb = (unsigned short*)(ws + ((size_t)133 << 20));  // 256 KB

  // weights f32 -> bf16 (+ S transpose)
  k_cvt<<<(KDim * Hdim / 4 + 255) / 256, 256, 0, stream>>>(
      (const float4*)qw, (uint2v*)qwb, KDim * Hdim / 4);
  k_cvt<<<(Hdim * Hdim / 4 + 255) / 256, 256, 0, stream>>>(
      (const float4*)gw, (uint2v*)gwb, Hdim * Hdim / 4);
  k_cvt<<<(Hdim * Hdim / 4 + 255) / 256, 256, 0, stream>>>(
      (const float4*)ow, (uint2v*)owb, Hdim * Hdim / 4);
  k_cvts<<<(4 * NH * HV * HK + 255) / 256, 256, 0, stream>>>(Srec, Stb);

  // x = rmsnorm(hidden) -> bf16
  k_rmsnorm<<<Mtok, 256, 0, stream>>>(hs, nw, (uint2v*)X);

  // fused q path -> Ob
  k_fused_q<<<(Mtok / 128) * (KDim / 128), 256, 0, stream>>>(
      X, qwb, Stb, vnw, Ob);

  // fused gate+o -> d_out f32
  k_fused_go<<<(Mtok / 128) * (Hdim / 128), 256, 0, stream>>>(
      X, Ob, gwb, owb, (float*)d_out);
}

// Round 11
// 433.090 us; speedup vs baseline: 1.0577x; 1.0577x over previous
//
#include <hip/hip_runtime.h>
#include <hip/hip_bf16.h>
#include <stdint.h>

typedef __attribute__((ext_vector_type(8))) short short8;
typedef __attribute__((ext_vector_type(4))) float floatx4;
typedef __attribute__((ext_vector_type(2))) unsigned int uint2v;

#define DEV static __device__ __forceinline__

DEV unsigned short f2bs(float f) {           // f32 -> bf16 bits, RNE
  union { float f; unsigned u; } v; v.f = f;
  unsigned u = v.u;
  u += 0x7fffu + ((u >> 16) & 1u);
  return (unsigned short)(u >> 16);
}
DEV float bs2f(unsigned short s) {
  union { unsigned u; float f; } v; v.u = ((unsigned)s) << 16;
  return v.f;
}
DEV unsigned pack2(float a, float b) {
  return (unsigned)f2bs(a) | ((unsigned)f2bs(b) << 16);
}

DEV void gload_lds16(const void* g, void* l) {
  __builtin_amdgcn_global_load_lds(
      (const __attribute__((address_space(1))) void*)g,
      (__attribute__((address_space(3))) void*)l, 16, 0, 0);
}

static constexpr int Hdim = 1024;
static constexpr int KDim = 512;
static constexpr int NH = 16;
static constexpr int HK = 32;
static constexpr int HV = 64;
static constexpr int Mtok = 4 * 8192;

// ---------- f32 -> bf16 convert (weights) ----------
__global__ __launch_bounds__(256) void k_cvt(const float4* __restrict__ in,
                                             uint2v* __restrict__ out, int n4) {
  int i = blockIdx.x * 256 + threadIdx.x;
  if (i >= n4) return;
  float4 v = in[i];
  uint2v o;
  o.x = pack2(v.x, v.y);
  o.y = pack2(v.z, v.w);
  out[i] = o;
}

// ---------- S -> S^T bf16:  St[b][h][v][k] = S[b][h][k][v] ----------
__global__ __launch_bounds__(256) void k_cvts(const float* __restrict__ S,
                                              unsigned short* __restrict__ St) {
  int i = blockIdx.x * 256 + threadIdx.x;      // over out idx, 4*16*64*32
  if (i >= 4 * NH * HV * HK) return;
  int k = i & 31, v = (i >> 5) & 63, bh = i >> 11;
  St[i] = f2bs(S[(size_t)(bh * HK + k) * HV + v]);
}

// ---------- rmsnorm(hidden) -> X bf16 ----------
__global__ __launch_bounds__(256) void k_rmsnorm(const float* __restrict__ hs,
                                                 const float* __restrict__ nw,
                                                 uint2v* __restrict__ X) {
  const int token = blockIdx.x;
  const int tid = threadIdx.x;
  float4 h = ((const float4*)(hs + (size_t)token * Hdim))[tid];
  float ss = h.x * h.x + h.y * h.y + h.z * h.z + h.w * h.w;
#pragma unroll
  for (int off = 32; off > 0; off >>= 1) ss += __shfl_down(ss, off, 64);
  __shared__ float red[4];
  const int lane = tid & 63, wid = tid >> 6;
  if (lane == 0) red[wid] = ss;
  __syncthreads();
  float tot = red[0] + red[1] + red[2] + red[3];
  float sc = rsqrtf(tot * (1.0f / Hdim) + 1e-5f);
  float4 w = ((const float4*)nw)[tid];
  uint2v o;
  o.x = pack2(h.x * sc * w.x, h.y * sc * w.y);
  o.y = pack2(h.z * sc * w.z, h.w * sc * w.w);
  X[(size_t)token * 256 + tid] = o;
}

// ---------- 128^2 / BK=64 GEMM core v6: hybrid staging, pinned prefetch ----
// A (HBM-streamed): gload_lds into LDS, T2-swizzled, double-buffered (32 KB).
// B (L2-hot weights): global->register, double-buffered in regs.
// KEY FIX vs v5: a zero-cost compiler memory fence BETWEEN prefetch-issue and
// compute pins the B register-loads ABOVE the MFMA cluster (otherwise LLVM
// sinks them below compute to shorten live ranges -> serial L2 latency,
// r10: VGPR=120 proved b0/b1 were not co-live; 2x regression).
DEV void stageA(const unsigned short* __restrict__ Ag, const int K,
                const int k0, unsigned short* slot, const int tid) {
  char* dst = (char*)slot + tid * 16;
#pragma unroll
  for (int i = 0; i < 4; ++i)
    gload_lds16(Ag + (size_t)i * 32 * K + k0, dst + i * 4096);
}

DEV void loadB(const unsigned short* __restrict__ Bg, const int K,
               const int k0, short8 (&b)[2][4]) {
#pragma unroll
  for (int kk = 0; kk < 2; ++kk)
#pragma unroll
    for (int ni = 0; ni < 4; ++ni)
      b[kk][ni] = *(const short8*)&Bg[(size_t)ni * 16 * K + k0 + kk * 32];
}

DEV void computeA(const unsigned short* __restrict__ Asb,
                  const short8 (&b)[2][4], floatx4 (&acc)[4][4], const int wr,
                  const int frr, const int frk, const int aswz) {
#pragma unroll
  for (int kk = 0; kk < 2; ++kk) {
    short8 a[4];
#pragma unroll
    for (int mi = 0; mi < 4; ++mi)
      a[mi] = *(const short8*)
          &Asb[(wr * 64 + mi * 16 + frr) * 64 + ((kk * 32 + frk) ^ aswz)];
#pragma unroll
    for (int mi = 0; mi < 4; ++mi)
#pragma unroll
      for (int ni = 0; ni < 4; ++ni)
        acc[mi][ni] = __builtin_amdgcn_mfma_f32_16x16x32_bf16(
            a[mi], b[kk][ni], acc[mi][ni], 0, 0, 0);
  }
}

#define FENCE() asm volatile("" ::: "memory")
#define WAITSYNC()                                   \
  asm volatile("s_waitcnt vmcnt(0)" ::: "memory");   \
  __builtin_amdgcn_s_barrier();                      \
  FENCE()

// LDS: 2 slots x 8192 shorts (32 KB total). K must be a multiple of 128.
DEV void gemm128h(const unsigned short* __restrict__ A,
                  const unsigned short* __restrict__ Bw, const int K,
                  const int m0, const int n0, unsigned short* LDS,
                  floatx4 (&acc)[4][4], const int tid) {
  const int lane = tid & 63;
  const int w = tid >> 6;
  const int wr = w >> 1, wc = w & 1;
  const int frr = lane & 15;
  const int frk = (lane >> 4) * 8;
  const int aswz = (frr & 7) * 8;
  const int r_a = tid >> 3;                         // 0..31
  const int c_src = ((tid & 7) ^ (r_a & 7)) * 8;    // pre-swizzled col
  const unsigned short* Ag = A + (size_t)(m0 + r_a) * K + c_src;
  const unsigned short* Bg = Bw + (size_t)(n0 + wc * 64 + frr) * K + frk;
  const int NT = K >> 6;                            // even (K%128==0)

  short8 b0[2][4], b1[2][4];
  // prologue: tile 0 -> slot0 + b0
  stageA(Ag, K, 0, LDS, tid);
  loadB(Bg, K, 0, b0);
  WAITSYNC();

  for (int t = 0; t < NT; t += 2) {
    // even step: prefetch t+1 -> slot1/b1 (pinned), compute slot0/b0
    if (t + 1 < NT) {
      stageA(Ag, K, (t + 1) * 64, LDS + 8192, tid);
      loadB(Bg, K, (t + 1) * 64, b1);
    }
    FENCE();                      // pin prefetch issue ABOVE the compute
    computeA(LDS, b0, acc, wr, frr, frk, aswz);
    if (t + 1 < NT) {
      WAITSYNC();
    }
    // odd step: prefetch t+2 -> slot0/b0 (pinned), compute slot1/b1
    if (t + 1 < NT) {
      if (t + 2 < NT) {
        stageA(Ag, K, (t + 2) * 64, LDS, tid);
        loadB(Bg, K, (t + 2) * 64, b0);
      }
      FENCE();
      computeA(LDS + 8192, b1, acc, wr, frr, frk, aswz);
      if (t + 2 < NT) {
        WAITSYNC();
      }
    }
  }
  __syncthreads();
}

// ---------- fused gate+o:  out = sigmoid(X@gw^T) * (Ob@ow^T), f32 ----------
// 1D grid 2048; XCD-chunked, m-major within chunk (A-tile L2-resident).
__global__ __launch_bounds__(256, 2) void k_fused_go(
    const unsigned short* __restrict__ X, const unsigned short* __restrict__ Ob,
    const unsigned short* __restrict__ gwb,
    const unsigned short* __restrict__ owb, float* __restrict__ out) {
  __shared__ unsigned short LDS[2 * 128 * 64];   // 32 KB (2 A-slots)
  const int tid = threadIdx.x;
  const int lane = tid & 63;
  const int w = tid >> 6;
  const int wr = w >> 1, wc = w & 1;
  const int bid = blockIdx.x;               // nwg = 2048 (multiple of 8)
  const int v = (bid & 7) * 256 + (bid >> 3);
  const int m0 = (v >> 3) * 128;            // m-major within XCD chunk
  const int n0 = (v & 7) * 128;

  floatx4 acc[4][4];
#pragma unroll
  for (int i = 0; i < 4; ++i)
#pragma unroll
    for (int j = 0; j < 4; ++j) acc[i][j] = (floatx4){0.f, 0.f, 0.f, 0.f};

  // pass 1: gate
  gemm128h(X, gwb, Hdim, m0, n0, LDS, acc, tid);

  // sigmoid -> packed bf16 stash
  unsigned pg[4][4][2];
#pragma unroll
  for (int mi = 0; mi < 4; ++mi)
#pragma unroll
    for (int ni = 0; ni < 4; ++ni) {
      float s0 = 1.0f / (1.0f + __expf(-acc[mi][ni][0]));
      float s1 = 1.0f / (1.0f + __expf(-acc[mi][ni][1]));
      float s2 = 1.0f / (1.0f + __expf(-acc[mi][ni][2]));
      float s3 = 1.0f / (1.0f + __expf(-acc[mi][ni][3]));
      pg[mi][ni][0] = pack2(s0, s1);
      pg[mi][ni][1] = pack2(s2, s3);
      acc[mi][ni] = (floatx4){0.f, 0.f, 0.f, 0.f};
    }

  // pass 2: o-proj
  gemm128h(Ob, owb, Hdim, m0, n0, LDS, acc, tid);

  // epilogue: C/D layout col = lane&15, row = (lane>>4)*4 + r
  const int rb = (lane >> 4) * 4;
#pragma unroll
  for (int mi = 0; mi < 4; ++mi)
#pragma unroll
    for (int ni = 0; ni < 4; ++ni) {
      const int n = n0 + wc * 64 + ni * 16 + (lane & 15);
#pragma unroll
      for (int r = 0; r < 4; ++r) {
        const int m = m0 + wr * 64 + mi * 16 + rb + r;
        float g = bs2f((unsigned short)(pg[mi][ni][r >> 1] >> ((r & 1) * 16)));
        out[(size_t)m * Hdim + n] = g * acc[mi][ni][r];
      }
    }
}

// ---------- fused q-path: q=X@qw^T -> L2-normalize per head -> @S -> rmsnorm
// tile: 128 tokens x 128 q-dims = 4 full heads. Writes Ob bf16 directly.
__global__ __launch_bounds__(256, 2) void k_fused_q(
    const unsigned short* __restrict__ X, const unsigned short* __restrict__ qwb,
    const unsigned short* __restrict__ St, const float* __restrict__ vnw,
    unsigned short* __restrict__ Ob) {
  __shared__ unsigned short LD[128 * 128];  // 32 KB: GEMM dbuf, then q-tile
  const int tid = threadIdx.x;
  const int lane = tid & 63;
  const int w = tid >> 6;
  const int wr = w >> 1, wc = w & 1;
  const int bid = blockIdx.x;               // nwg = 1024
  const int v = (bid & 7) * 128 + (bid >> 3);
  const int m0 = (v >> 2) * 128;
  const int n0 = (v & 3) * 128;             // q-dim base; heads h0..h0+3
  const int h0 = n0 >> 5;
  const int batch = m0 >> 13;               // 8192 tokens per batch

  floatx4 acc[4][4];
#pragma unroll
  for (int i = 0; i < 4; ++i)
#pragma unroll
    for (int j = 0; j < 4; ++j) acc[i][j] = (floatx4){0.f, 0.f, 0.f, 0.f};

  gemm128h(X, qwb, Hdim, m0, n0, LD, acc, tid);

  // per-(row,head) L2 norm over 32 dims = 2 ni-frags x 16 lanes, then scale,
  // then store normalized q bf16 into swizzled LDS tile qt[m][c^((m&7)*8)].
  const int rb = (lane >> 4) * 4;
  const int frr = lane & 15;
#pragma unroll
  for (int mi = 0; mi < 4; ++mi)
#pragma unroll
    for (int p = 0; p < 2; ++p) {      // head-half: ni = 2p, 2p+1
#pragma unroll
      for (int r = 0; r < 4; ++r) {
        float v0 = acc[mi][2 * p][r], v1 = acc[mi][2 * p + 1][r];
        float ss = v0 * v0 + v1 * v1;
        ss += __shfl_xor(ss, 1, 64);
        ss += __shfl_xor(ss, 2, 64);
        ss += __shfl_xor(ss, 4, 64);
        ss += __shfl_xor(ss, 8, 64);
        const float inv = 1.0f / fmaxf(sqrtf(ss), 1e-12f);
        const int m = wr * 64 + mi * 16 + rb + r;
        const int c0 = wc * 64 + p * 32 + frr;
        const int sw = (m & 7) * 8;
        LD[m * 128 + (c0 ^ sw)] = f2bs(v0 * inv);
        LD[m * 128 + ((c0 + 16) ^ sw)] = f2bs(v1 * inv);
      }
    }
  __syncthreads();

  // contraction: per head hh, o[32w..32w+31][64] = qn[.,32] @ St[h]^T via MFMA
  // wave w owns token rows m = w*32 .. w*32+31.
  const int frk = (lane >> 4) * 8;   // k sub-range within K=32
  float wv[4];
#pragma unroll
  for (int ni = 0; ni < 4; ++ni) wv[ni] = vnw[ni * 16 + frr];

#pragma unroll
  for (int hh = 0; hh < 4; ++hh) {
    const unsigned short* Sp =
        St + (size_t)(batch * NH + h0 + hh) * (HV * HK);
    short8 bfr[4];
#pragma unroll
    for (int ni = 0; ni < 4; ++ni)
      bfr[ni] = *(const short8*)&Sp[(ni * 16 + frr) * HK + frk];
    floatx4 acc2[2][4];
#pragma unroll
    for (int i = 0; i < 2; ++i)
#pragma unroll
      for (int j = 0; j < 4; ++j) acc2[i][j] = (floatx4){0.f, 0.f, 0.f, 0.f};
    short8 af[2];
#pragma unroll
    for (int mi2 = 0; mi2 < 2; ++mi2) {
      const int m = w * 32 + mi2 * 16 + frr;
      af[mi2] = *(const short8*)&LD[m * 128 + ((hh * 32 + frk) ^ ((m & 7) * 8))];
    }
#pragma unroll
    for (int mi2 = 0; mi2 < 2; ++mi2)
#pragma unroll
      for (int ni = 0; ni < 4; ++ni)
        acc2[mi2][ni] = __builtin_amdgcn_mfma_f32_16x16x32_bf16(
            af[mi2], bfr[ni], acc2[mi2][ni], 0, 0, 0);

    // v-rmsnorm over 64 dims = 4 ni-frags x 16 lanes; write Ob bf16
#pragma unroll
    for (int mi2 = 0; mi2 < 2; ++mi2)
#pragma unroll
      for (int r = 0; r < 4; ++r) {
        float ss2 = 0.f;
#pragma unroll
        for (int ni = 0; ni < 4; ++ni) ss2 += acc2[mi2][ni][r] * acc2[mi2][ni][r];
        ss2 += __shfl_xor(ss2, 1, 64);
        ss2 += __shfl_xor(ss2, 2, 64);
        ss2 += __shfl_xor(ss2, 4, 64);
        ss2 += __shfl_xor(ss2, 8, 64);
        const float sc = rsqrtf(ss2 * (1.0f / HV) + 1e-5f);
        const int m = m0 + w * 32 + mi2 * 16 + rb + r;
        unsigned short* Op = Ob + (size_t)m * Hdim + (h0 + hh) * HV;
#pragma unroll
        for (int ni = 0; ni < 4; ++ni)
          Op[ni * 16 + frr] = f2bs(acc2[mi2][ni][r] * sc * wv[ni]);
      }
  }
}

extern "C" void kernel_launch(void* const* d_in, const int* in_sizes, int n_in,
                              void* d_out, int out_size, void* d_ws, size_t ws_size,
                              hipStream_t stream) {
  const float* hs = (const float*)d_in[0];
  const float* Srec = (const float*)d_in[1];
  const float* nw = (const float*)d_in[2];
  const float* qw = (const float*)d_in[3];
  const float* vnw = (const float*)d_in[4];
  const float* ow = (const float*)d_in[5];
  const float* gw = (const float*)d_in[6];

  char* ws = (char*)d_ws;
  unsigned short* X = (unsigned short*)(ws);                          // 64 MB bf16 [M,H]
  unsigned short* Ob = (unsigned short*)(ws + ((size_t)64 << 20));    // 64 MB bf16 [M,VD]
  unsigned short* qwb = (unsigned short*)(ws + ((size_t)128 << 20));  // 1 MB
  unsigned short* gwb = (unsigned short*)(ws + ((size_t)129 << 20));  // 2 MB
  unsigned short* owb = (unsigned short*)(ws + ((size_t)131 << 20));  // 2 MB
  unsigned short* Stb = (unsigned short*)(ws + ((size_t)133 << 20));  // 256 KB

  // weights f32 -> bf16 (+ S transpose)
  k_cvt<<<(KDim * Hdim / 4 + 255) / 256, 256, 0, stream>>>(
      (const float4*)qw, (uint2v*)qwb, KDim * Hdim / 4);
  k_cvt<<<(Hdim * Hdim / 4 + 255) / 256, 256, 0, stream>>>(
      (const float4*)gw, (uint2v*)gwb, Hdim * Hdim / 4);
  k_cvt<<<(Hdim * Hdim / 4 + 255) / 256, 256, 0, stream>>>(
      (const float4*)ow, (uint2v*)owb, Hdim * Hdim / 4);
  k_cvts<<<(4 * NH * HV * HK + 255) / 256, 256, 0, stream>>>(Srec, Stb);

  // x = rmsnorm(hidden) -> bf16
  k_rmsnorm<<<Mtok, 256, 0, stream>>>(hs, nw, (uint2v*)X);

  // fused q path -> Ob
  k_fused_q<<<(Mtok / 128) * (KDim / 128), 256, 0, stream>>>(
      X, qwb, Stb, vnw, Ob);

  // fused gate+o -> d_out f32
  k_fused_go<<<(Mtok / 128) * (Hdim / 128), 256, 0, stream>>>(
      X, Ob, gwb, owb, (float*)d_out);
}

// Round 12
// 432.214 us; speedup vs baseline: 1.0598x; 1.0020x over previous
//
#include <hip/hip_runtime.h>
#include <hip/hip_bf16.h>
#include <stdint.h>

typedef __attribute__((ext_vector_type(8))) short short8;
typedef __attribute__((ext_vector_type(4))) float floatx4;
typedef __attribute__((ext_vector_type(2))) unsigned int uint2v;

#define DEV static __device__ __forceinline__

DEV unsigned short f2bs(float f) {           // f32 -> bf16 bits, RNE
  union { float f; unsigned u; } v; v.f = f;
  unsigned u = v.u;
  u += 0x7fffu + ((u >> 16) & 1u);
  return (unsigned short)(u >> 16);
}
DEV float bs2f(unsigned short s) {
  union { unsigned u; float f; } v; v.u = ((unsigned)s) << 16;
  return v.f;
}
DEV unsigned pack2(float a, float b) {
  return (unsigned)f2bs(a) | ((unsigned)f2bs(b) << 16);
}

DEV void gload_lds16(const void* g, void* l) {
  __builtin_amdgcn_global_load_lds(
      (const __attribute__((address_space(1))) void*)g,
      (__attribute__((address_space(3))) void*)l, 16, 0, 0);
}

static constexpr int Hdim = 1024;
static constexpr int KDim = 512;
static constexpr int NH = 16;
static constexpr int HK = 32;
static constexpr int HV = 64;
static constexpr int Mtok = 4 * 8192;

// ---------- f32 -> bf16 convert (weights) ----------
__global__ __launch_bounds__(256) void k_cvt(const float4* __restrict__ in,
                                             uint2v* __restrict__ out, int n4) {
  int i = blockIdx.x * 256 + threadIdx.x;
  if (i >= n4) return;
  float4 v = in[i];
  uint2v o;
  o.x = pack2(v.x, v.y);
  o.y = pack2(v.z, v.w);
  out[i] = o;
}

// ---------- S -> S^T bf16:  St[b][h][v][k] = S[b][h][k][v] ----------
__global__ __launch_bounds__(256) void k_cvts(const float* __restrict__ S,
                                              unsigned short* __restrict__ St) {
  int i = blockIdx.x * 256 + threadIdx.x;      // over out idx, 4*16*64*32
  if (i >= 4 * NH * HV * HK) return;
  int k = i & 31, v = (i >> 5) & 63, bh = i >> 11;
  St[i] = f2bs(S[(size_t)(bh * HK + k) * HV + v]);
}

// ---------- rmsnorm(hidden) -> X bf16 ----------
__global__ __launch_bounds__(256) void k_rmsnorm(const float* __restrict__ hs,
                                                 const float* __restrict__ nw,
                                                 uint2v* __restrict__ X) {
  const int token = blockIdx.x;
  const int tid = threadIdx.x;
  float4 h = ((const float4*)(hs + (size_t)token * Hdim))[tid];
  float ss = h.x * h.x + h.y * h.y + h.z * h.z + h.w * h.w;
#pragma unroll
  for (int off = 32; off > 0; off >>= 1) ss += __shfl_down(ss, off, 64);
  __shared__ float red[4];
  const int lane = tid & 63, wid = tid >> 6;
  if (lane == 0) red[wid] = ss;
  __syncthreads();
  float tot = red[0] + red[1] + red[2] + red[3];
  float sc = rsqrtf(tot * (1.0f / Hdim) + 1e-5f);
  float4 w = ((const float4*)nw)[tid];
  uint2v o;
  o.x = pack2(h.x * sc * w.x, h.y * sc * w.y);
  o.y = pack2(h.z * sc * w.z, h.w * sc * w.w);
  X[(size_t)token * 256 + tid] = o;
}

// ---------- 128^2 / BK=64 GEMM core v6: hybrid staging, pinned prefetch ----
// A (HBM-streamed): gload_lds into LDS, T2-swizzled, double-buffered (32 KB).
// B (L2-hot weights): global->register, double-buffered in regs.
// KEY FIX vs v5: a zero-cost compiler memory fence BETWEEN prefetch-issue and
// compute pins the B register-loads ABOVE the MFMA cluster (otherwise LLVM
// sinks them below compute to shorten live ranges -> serial L2 latency,
// r10: VGPR=120 proved b0/b1 were not co-live; 2x regression).
DEV void stageA(const unsigned short* __restrict__ Ag, const int K,
                const int k0, unsigned short* slot, const int tid) {
  char* dst = (char*)slot + tid * 16;
#pragma unroll
  for (int i = 0; i < 4; ++i)
    gload_lds16(Ag + (size_t)i * 32 * K + k0, dst + i * 4096);
}

DEV void loadB(const unsigned short* __restrict__ Bg, const int K,
               const int k0, short8 (&b)[2][4]) {
#pragma unroll
  for (int kk = 0; kk < 2; ++kk)
#pragma unroll
    for (int ni = 0; ni < 4; ++ni)
      b[kk][ni] = *(const short8*)&Bg[(size_t)ni * 16 * K + k0 + kk * 32];
}

DEV void computeA(const unsigned short* __restrict__ Asb,
                  const short8 (&b)[2][4], floatx4 (&acc)[4][4], const int wr,
                  const int frr, const int frk, const int aswz) {
#pragma unroll
  for (int kk = 0; kk < 2; ++kk) {
    short8 a[4];
#pragma unroll
    for (int mi = 0; mi < 4; ++mi)
      a[mi] = *(const short8*)
          &Asb[(wr * 64 + mi * 16 + frr) * 64 + ((kk * 32 + frk) ^ aswz)];
#pragma unroll
    for (int mi = 0; mi < 4; ++mi)
#pragma unroll
      for (int ni = 0; ni < 4; ++ni)
        acc[mi][ni] = __builtin_amdgcn_mfma_f32_16x16x32_bf16(
            a[mi], b[kk][ni], acc[mi][ni], 0, 0, 0);
  }
}

#define FENCE() asm volatile("" ::: "memory")
#define WAITSYNC()                                   \
  asm volatile("s_waitcnt vmcnt(0)" ::: "memory");   \
  __builtin_amdgcn_s_barrier();                      \
  FENCE()

// LDS: 2 slots x 8192 shorts (32 KB total). K must be a multiple of 128.
DEV void gemm128h(const unsigned short* __restrict__ A,
                  const unsigned short* __restrict__ Bw, const int K,
                  const int m0, const int n0, unsigned short* LDS,
                  floatx4 (&acc)[4][4], const int tid) {
  const int lane = tid & 63;
  const int w = tid >> 6;
  const int wr = w >> 1, wc = w & 1;
  const int frr = lane & 15;
  const int frk = (lane >> 4) * 8;
  const int aswz = (frr & 7) * 8;
  const int r_a = tid >> 3;                         // 0..31
  const int c_src = ((tid & 7) ^ (r_a & 7)) * 8;    // pre-swizzled col
  const unsigned short* Ag = A + (size_t)(m0 + r_a) * K + c_src;
  const unsigned short* Bg = Bw + (size_t)(n0 + wc * 64 + frr) * K + frk;
  const int NT = K >> 6;                            // even (K%128==0)

  short8 b0[2][4], b1[2][4];
  // prologue: tile 0 -> slot0 + b0
  stageA(Ag, K, 0, LDS, tid);
  loadB(Bg, K, 0, b0);
  WAITSYNC();

  for (int t = 0; t < NT; t += 2) {
    // even step: prefetch t+1 -> slot1/b1 (pinned), compute slot0/b0
    if (t + 1 < NT) {
      stageA(Ag, K, (t + 1) * 64, LDS + 8192, tid);
      loadB(Bg, K, (t + 1) * 64, b1);
    }
    FENCE();                      // pin prefetch issue ABOVE the compute
    computeA(LDS, b0, acc, wr, frr, frk, aswz);
    if (t + 1 < NT) {
      WAITSYNC();
    }
    // odd step: prefetch t+2 -> slot0/b0 (pinned), compute slot1/b1
    if (t + 1 < NT) {
      if (t + 2 < NT) {
        stageA(Ag, K, (t + 2) * 64, LDS, tid);
        loadB(Bg, K, (t + 2) * 64, b0);
      }
      FENCE();
      computeA(LDS + 8192, b1, acc, wr, frr, frk, aswz);
      if (t + 2 < NT) {
        WAITSYNC();
      }
    }
  }
  __syncthreads();
}

// ---------- fused gate+o:  out = sigmoid(X@gw^T) * (Ob@ow^T), f32 ----------
// 1D grid 2048; XCD-chunked, m-major within chunk (A-tile L2-resident).
__global__ __launch_bounds__(256, 2) void k_fused_go(
    const unsigned short* __restrict__ X, const unsigned short* __restrict__ Ob,
    const unsigned short* __restrict__ gwb,
    const unsigned short* __restrict__ owb, float* __restrict__ out) {
  __shared__ unsigned short LDS[2 * 128 * 64];   // 32 KB (2 A-slots)
  const int tid = threadIdx.x;
  const int lane = tid & 63;
  const int w = tid >> 6;
  const int wr = w >> 1, wc = w & 1;
  const int bid = blockIdx.x;               // nwg = 2048 (multiple of 8)
  const int v = (bid & 7) * 256 + (bid >> 3);
  const int m0 = (v >> 3) * 128;            // m-major within XCD chunk
  const int n0 = (v & 7) * 128;

  floatx4 acc[4][4];
#pragma unroll
  for (int i = 0; i < 4; ++i)
#pragma unroll
    for (int j = 0; j < 4; ++j) acc[i][j] = (floatx4){0.f, 0.f, 0.f, 0.f};

  // pass 1: gate
  gemm128h(X, gwb, Hdim, m0, n0, LDS, acc, tid);

  // sigmoid -> packed bf16 stash
  unsigned pg[4][4][2];
#pragma unroll
  for (int mi = 0; mi < 4; ++mi)
#pragma unroll
    for (int ni = 0; ni < 4; ++ni) {
      float s0 = 1.0f / (1.0f + __expf(-acc[mi][ni][0]));
      float s1 = 1.0f / (1.0f + __expf(-acc[mi][ni][1]));
      float s2 = 1.0f / (1.0f + __expf(-acc[mi][ni][2]));
      float s3 = 1.0f / (1.0f + __expf(-acc[mi][ni][3]));
      pg[mi][ni][0] = pack2(s0, s1);
      pg[mi][ni][1] = pack2(s2, s3);
      acc[mi][ni] = (floatx4){0.f, 0.f, 0.f, 0.f};
    }

  // pass 2: o-proj
  gemm128h(Ob, owb, Hdim, m0, n0, LDS, acc, tid);

  // epilogue: C/D layout col = lane&15, row = (lane>>4)*4 + r
  const int rb = (lane >> 4) * 4;
#pragma unroll
  for (int mi = 0; mi < 4; ++mi)
#pragma unroll
    for (int ni = 0; ni < 4; ++ni) {
      const int n = n0 + wc * 64 + ni * 16 + (lane & 15);
#pragma unroll
      for (int r = 0; r < 4; ++r) {
        const int m = m0 + wr * 64 + mi * 16 + rb + r;
        float g = bs2f((unsigned short)(pg[mi][ni][r >> 1] >> ((r & 1) * 16)));
        out[(size_t)m * Hdim + n] = g * acc[mi][ni][r];
      }
    }
}

// ---------- fused q-path: q=X@qw^T -> L2-normalize per head -> @S -> rmsnorm
// tile: 128 tokens x 128 q-dims = 4 full heads. Writes Ob bf16 directly.
__global__ __launch_bounds__(256, 2) void k_fused_q(
    const unsigned short* __restrict__ X, const unsigned short* __restrict__ qwb,
    const unsigned short* __restrict__ St, const float* __restrict__ vnw,
    unsigned short* __restrict__ Ob) {
  __shared__ unsigned short LD[128 * 128];  // 32 KB: GEMM dbuf, then q-tile
  const int tid = threadIdx.x;
  const int lane = tid & 63;
  const int w = tid >> 6;
  const int wr = w >> 1, wc = w & 1;
  const int bid = blockIdx.x;               // nwg = 1024
  const int v = (bid & 7) * 128 + (bid >> 3);
  const int m0 = (v >> 2) * 128;
  const int n0 = (v & 3) * 128;             // q-dim base; heads h0..h0+3
  const int h0 = n0 >> 5;
  const int batch = m0 >> 13;               // 8192 tokens per batch

  floatx4 acc[4][4];
#pragma unroll
  for (int i = 0; i < 4; ++i)
#pragma unroll
    for (int j = 0; j < 4; ++j) acc[i][j] = (floatx4){0.f, 0.f, 0.f, 0.f};

  gemm128h(X, qwb, Hdim, m0, n0, LD, acc, tid);

  // per-(row,head) L2 norm over 32 dims = 2 ni-frags x 16 lanes, then scale,
  // then store normalized q bf16 into swizzled LDS tile qt[m][c^((m&7)*8)].
  const int rb = (lane >> 4) * 4;
  const int frr = lane & 15;
#pragma unroll
  for (int mi = 0; mi < 4; ++mi)
#pragma unroll
    for (int p = 0; p < 2; ++p) {      // head-half: ni = 2p, 2p+1
#pragma unroll
      for (int r = 0; r < 4; ++r) {
        float v0 = acc[mi][2 * p][r], v1 = acc[mi][2 * p + 1][r];
        float ss = v0 * v0 + v1 * v1;
        ss += __shfl_xor(ss, 1, 64);
        ss += __shfl_xor(ss, 2, 64);
        ss += __shfl_xor(ss, 4, 64);
        ss += __shfl_xor(ss, 8, 64);
        const float inv = 1.0f / fmaxf(sqrtf(ss), 1e-12f);
        const int m = wr * 64 + mi * 16 + rb + r;
        const int c0 = wc * 64 + p * 32 + frr;
        const int sw = (m & 7) * 8;
        LD[m * 128 + (c0 ^ sw)] = f2bs(v0 * inv);
        LD[m * 128 + ((c0 + 16) ^ sw)] = f2bs(v1 * inv);
      }
    }
  __syncthreads();

  // contraction: per head hh, o[32w..32w+31][64] = qn[.,32] @ St[h]^T via MFMA
  // wave w owns token rows m = w*32 .. w*32+31.
  const int frk = (lane >> 4) * 8;   // k sub-range within K=32
  float wv[4];
#pragma unroll
  for (int ni = 0; ni < 4; ++ni) wv[ni] = vnw[ni * 16 + frr];

#pragma unroll
  for (int hh = 0; hh < 4; ++hh) {
    const unsigned short* Sp =
        St + (size_t)(batch * NH + h0 + hh) * (HV * HK);
    short8 bfr[4];
#pragma unroll
    for (int ni = 0; ni < 4; ++ni)
      bfr[ni] = *(const short8*)&Sp[(ni * 16 + frr) * HK + frk];
    floatx4 acc2[2][4];
#pragma unroll
    for (int i = 0; i < 2; ++i)
#pragma unroll
      for (int j = 0; j < 4; ++j) acc2[i][j] = (floatx4){0.f, 0.f, 0.f, 0.f};
    short8 af[2];
#pragma unroll
    for (int mi2 = 0; mi2 < 2; ++mi2) {
      const int m = w * 32 + mi2 * 16 + frr;
      af[mi2] = *(const short8*)&LD[m * 128 + ((hh * 32 + frk) ^ ((m & 7) * 8))];
    }
#pragma unroll
    for (int mi2 = 0; mi2 < 2; ++mi2)
#pragma unroll
      for (int ni = 0; ni < 4; ++ni)
        acc2[mi2][ni] = __builtin_amdgcn_mfma_f32_16x16x32_bf16(
            af[mi2], bfr[ni], acc2[mi2][ni], 0, 0, 0);

    // v-rmsnorm over 64 dims = 4 ni-frags x 16 lanes; write Ob bf16
#pragma unroll
    for (int mi2 = 0; mi2 < 2; ++mi2)
#pragma unroll
      for (int r = 0; r < 4; ++r) {
        float ss2 = 0.f;
#pragma unroll
        for (int ni = 0; ni < 4; ++ni) ss2 += acc2[mi2][ni][r] * acc2[mi2][ni][r];
        ss2 += __shfl_xor(ss2, 1, 64);
        ss2 += __shfl_xor(ss2, 2, 64);
        ss2 += __shfl_xor(ss2, 4, 64);
        ss2 += __shfl_xor(ss2, 8, 64);
        const float sc = rsqrtf(ss2 * (1.0f / HV) + 1e-5f);
        const int m = m0 + w * 32 + mi2 * 16 + rb + r;
        unsigned short* Op = Ob + (size_t)m * Hdim + (h0 + hh) * HV;
#pragma unroll
        for (int ni = 0; ni < 4; ++ni)
          Op[ni * 16 + frr] = f2bs(acc2[mi2][ni][r] * sc * wv[ni]);
      }
  }
}

extern "C" void kernel_launch(void* const* d_in, const int* in_sizes, int n_in,
                              void* d_out, int out_size, void* d_ws, size_t ws_size,
                              hipStream_t stream) {
  const float* hs = (const float*)d_in[0];
  const float* Srec = (const float*)d_in[1];
  const float* nw = (const float*)d_in[2];
  const float* qw = (const float*)d_in[3];
  const float* vnw = (const float*)d_in[4];
  const float* ow = (const float*)d_in[5];
  const float* gw = (const float*)d_in[6];

  char* ws = (char*)d_ws;
  unsigned short* X = (unsigned short*)(ws);                          // 64 MB bf16 [M,H]
  unsigned short* Ob = (unsigned short*)(ws + ((size_t)64 << 20));    // 64 MB bf16 [M,VD]
  unsigned short* qwb = (unsigned short*)(ws + ((size_t)128 << 20));  // 1 MB
  unsigned short* gwb = (unsigned short*)(ws + ((size_t)129 << 20));  // 2 MB
  unsigned short* owb = (unsigned short*)(ws + ((size_t)131 << 20));  // 2 MB
  unsigned short* Stb = (unsigned short*)(ws + ((size_t)133 << 20));  // 256 KB

  // weights f32 -> bf16 (+ S transpose)
  k_cvt<<<(KDim * Hdim / 4 + 255) / 256, 256, 0, stream>>>(
      (const float4*)qw, (uint2v*)qwb, KDim * Hdim / 4);
  k_cvt<<<(Hdim * Hdim / 4 + 255) / 256, 256, 0, stream>>>(
      (const float4*)gw, (uint2v*)gwb, Hdim * Hdim / 4);
  k_cvt<<<(Hdim * Hdim / 4 + 255) / 256, 256, 0, stream>>>(
      (const float4*)ow, (uint2v*)owb, Hdim * Hdim / 4);
  k_cvts<<<(4 * NH * HV * HK + 255) / 256, 256, 0, stream>>>(Srec, Stb);

  // x = rmsnorm(hidden) -> bf16
  k_rmsnorm<<<Mtok, 256, 0, stream>>>(hs, nw, (uint2v*)X);

  // fused q path -> Ob
  k_fused_q<<<(Mtok / 128) * (KDim / 128), 256, 0, stream>>>(
      X, qwb, Stb, vnw, Ob);

  // fused gate+o -> d_out f32
  k_fused_go<<<(Mtok / 128) * (Hdim / 128), 256, 0, stream>>>(
      X, Ob, gwb, owb, (float*)d_out);
}

// Round 13
// 294.782 us; speedup vs baseline: 1.5539x; 1.4662x over previous
//
#include <hip/hip_runtime.h>
#include <hip/hip_bf16.h>
#include <stdint.h>

typedef __attribute__((ext_vector_type(8))) short short8;
typedef __attribute__((ext_vector_type(4))) float floatx4;
typedef __attribute__((ext_vector_type(2))) unsigned int uint2v;

#define DEV static __device__ __forceinline__
#define FENCE() asm volatile("" ::: "memory")

DEV unsigned short f2bs(float f) {           // f32 -> bf16 bits, RNE
  union { float f; unsigned u; } v; v.f = f;
  unsigned u = v.u;
  u += 0x7fffu + ((u >> 16) & 1u);
  return (unsigned short)(u >> 16);
}
DEV float bs2f(unsigned short s) {
  union { unsigned u; float f; } v; v.u = ((unsigned)s) << 16;
  return v.f;
}
DEV unsigned pack2(float a, float b) {
  return (unsigned)f2bs(a) | ((unsigned)f2bs(b) << 16);
}

DEV void gload_lds16(const void* g, void* l) {
  __builtin_amdgcn_global_load_lds(
      (const __attribute__((address_space(1))) void*)g,
      (__attribute__((address_space(3))) void*)l, 16, 0, 0);
}

static constexpr int Hdim = 1024;
static constexpr int KDim = 512;
static constexpr int NH = 16;
static constexpr int HK = 32;
static constexpr int HV = 64;
static constexpr int Mtok = 4 * 8192;

// ---------- f32 -> bf16 convert (weights) ----------
__global__ __launch_bounds__(256) void k_cvt(const float4* __restrict__ in,
                                             uint2v* __restrict__ out, int n4) {
  int i = blockIdx.x * 256 + threadIdx.x;
  if (i >= n4) return;
  float4 v = in[i];
  uint2v o;
  o.x = pack2(v.x, v.y);
  o.y = pack2(v.z, v.w);
  out[i] = o;
}

// ---------- S -> S^T bf16:  St[b][h][v][k] = S[b][h][k][v] ----------
__global__ __launch_bounds__(256) void k_cvts(const float* __restrict__ S,
                                              unsigned short* __restrict__ St) {
  int i = blockIdx.x * 256 + threadIdx.x;      // over out idx, 4*16*64*32
  if (i >= 4 * NH * HV * HK) return;
  int k = i & 31, v = (i >> 5) & 63, bh = i >> 11;
  St[i] = f2bs(S[(size_t)(bh * HK + k) * HV + v]);
}

// ---------- rmsnorm(hidden) -> X bf16 ----------
__global__ __launch_bounds__(256) void k_rmsnorm(const float* __restrict__ hs,
                                                 const float* __restrict__ nw,
                                                 uint2v* __restrict__ X) {
  const int token = blockIdx.x;
  const int tid = threadIdx.x;
  float4 h = ((const float4*)(hs + (size_t)token * Hdim))[tid];
  float ss = h.x * h.x + h.y * h.y + h.z * h.z + h.w * h.w;
#pragma unroll
  for (int off = 32; off > 0; off >>= 1) ss += __shfl_down(ss, off, 64);
  __shared__ float red[4];
  const int lane = tid & 63, wid = tid >> 6;
  if (lane == 0) red[wid] = ss;
  __syncthreads();
  float tot = red[0] + red[1] + red[2] + red[3];
  float sc = rsqrtf(tot * (1.0f / Hdim) + 1e-5f);
  float4 w = ((const float4*)nw)[tid];
  uint2v o;
  o.x = pack2(h.x * sc * w.x, h.y * sc * w.y);
  o.y = pack2(h.z * sc * w.z, h.w * sc * w.w);
  X[(size_t)token * 256 + tid] = o;
}

// ---------- stage one 128x64 bf16 half-tile (T2 source-swizzle) ----------
DEV void stage_half(const unsigned short* __restrict__ G, int ldg,
                    unsigned short* lds, int tid) {
  const int r = tid >> 3;                              // 0..63
  const int c = ((tid & 7) ^ (r & 7)) * 8;             // pre-swizzled col
  const unsigned short* src = G + (size_t)r * ldg + c;
  char* dst = (char*)lds + tid * 16;
  gload_lds16(src, dst);
  gload_lds16(src + (size_t)64 * ldg, dst + 8192);     // rows 64..127 (same swz)
}

// ---------- 256^2 / BK=64 / 8-wave GEMM, 4-phase interleave + counted vmcnt
// Stage placement derived from read-drain points:
//   A-half of slot s is free after that tile's ph3 lgkm; B-half after ph2.
//   ph1: stage A0(t+1)  ph2: A1(t+1)  ph3: B0(t+2)  ph4: B1(t+2) + vmcnt(4).
// Steady state: entering ph1 outstanding = B01(t+1)=4 loads; ph4 wait keeps
// exactly B01(t+2). Tail: vmcnt(0) when t+2>=NT. Prologue: 6 halves+vmcnt(4).
// bf01 register-carried to q4 (ph4 has no ds_reads).
// EPI 1: bf16(sigmoid(acc)) -> Cout   EPI 2: f32(Gate[idx]*acc) -> Cout
template <int EPI>
__global__ __launch_bounds__(512, 2) void k_gemm256p(
    const unsigned short* __restrict__ A, const unsigned short* __restrict__ Bw,
    void* __restrict__ Cout, const unsigned short* __restrict__ Gate,
    const int N, const int K) {
  __shared__ unsigned short LDS[2][4][128 * 64];   // [slot][A0,A1,B0,B1] 128KB
  const int tid = threadIdx.x;
  const int lane = tid & 63;
  const int w = tid >> 6;              // 0..7
  const int wr = w >> 2, wc = w & 3;   // 2M x 4N wave grid
  const int wcH = wc >> 1;             // B half
  const int rB0 = (wc & 1) * 64;       // row base within B half

  // XCD-chunked swizzle (nwg % 8 == 0), n fastest within chunk -> A reuse
  const int nwg = gridDim.x;
  const int bid = blockIdx.x;
  const int cpx = nwg >> 3;
  const int v = (bid & 7) * cpx + (bid >> 3);
  const int ncols = N >> 8;
  const int row = v / ncols, col = v % ncols;
  const int m0 = row << 8, n0 = col << 8;

  floatx4 acc[8][4];
#pragma unroll
  for (int i = 0; i < 8; ++i)
#pragma unroll
    for (int j = 0; j < 4; ++j) acc[i][j] = (floatx4){0.f, 0.f, 0.f, 0.f};

  const unsigned short* Ab = A + (size_t)m0 * K;
  const unsigned short* Bb = Bw + (size_t)n0 * K;
  const int frr = lane & 15;
  const int frk = (lane >> 4) * 8;
  const int swz = (frr & 7) * 8;
  const int NT = K >> 6;   // >= 2

  // prologue: A0(0) A1(0) B0(0) B1(0) B0(1) B1(1); drain tile0 (keep B01(1))
  stage_half(Ab, K, LDS[0][0], tid);
  stage_half(Ab + (size_t)128 * K, K, LDS[0][1], tid);
  stage_half(Bb, K, LDS[0][2], tid);
  stage_half(Bb + (size_t)128 * K, K, LDS[0][3], tid);
  stage_half(Bb + 64, K, LDS[1][2], tid);
  stage_half(Bb + (size_t)128 * K + 64, K, LDS[1][3], tid);
  asm volatile("s_waitcnt vmcnt(4)" ::: "memory");
  __builtin_amdgcn_s_barrier();
  FENCE();

  for (int t = 0; t < NT; ++t) {
    const unsigned short* Ah = LDS[t & 1][wr];
    const unsigned short* Bh = LDS[t & 1][2 + wcH];
    short8 afl[2][4], afh[2][4], bf01[2][2], bf23[2][2];

    // ---- ph1: dsr af_lo(8)+bf01(4); stage A0(t+1); q1 = mi0-3 x ni0-1
#pragma unroll
    for (int kh = 0; kh < 2; ++kh)
#pragma unroll
      for (int mi = 0; mi < 4; ++mi)
        afl[kh][mi] = *(const short8*)
            &Ah[(mi * 16 + frr) * 64 + ((kh * 32 + frk) ^ swz)];
#pragma unroll
    for (int kh = 0; kh < 2; ++kh)
#pragma unroll
      for (int ni = 0; ni < 2; ++ni)
        bf01[kh][ni] = *(const short8*)
            &Bh[(rB0 + ni * 16 + frr) * 64 + ((kh * 32 + frk) ^ swz)];
    if (t + 1 < NT)
      stage_half(Ab + (size_t)(t + 1) * 64, K, LDS[(t + 1) & 1][0], tid);
    FENCE();
    __builtin_amdgcn_s_barrier();
    asm volatile("s_waitcnt lgkmcnt(0)" ::: "memory");
    __builtin_amdgcn_s_setprio(1);
#pragma unroll
    for (int kh = 0; kh < 2; ++kh)
#pragma unroll
      for (int mi = 0; mi < 4; ++mi)
#pragma unroll
        for (int ni = 0; ni < 2; ++ni)
          acc[mi][ni] = __builtin_amdgcn_mfma_f32_16x16x32_bf16(
              afl[kh][mi], bf01[kh][ni], acc[mi][ni], 0, 0, 0);
    __builtin_amdgcn_s_setprio(0);
    __builtin_amdgcn_s_barrier();

    // ---- ph2: dsr bf23(4); stage A1(t+1); q2 = mi0-3 x ni2-3
#pragma unroll
    for (int kh = 0; kh < 2; ++kh)
#pragma unroll
      for (int ni = 0; ni < 2; ++ni)
        bf23[kh][ni] = *(const short8*)
            &Bh[(rB0 + (ni + 2) * 16 + frr) * 64 + ((kh * 32 + frk) ^ swz)];
    if (t + 1 < NT)
      stage_half(Ab + (size_t)128 * K + (t + 1) * 64, K, LDS[(t + 1) & 1][1],
                 tid);
    FENCE();
    __builtin_amdgcn_s_barrier();
    asm volatile("s_waitcnt lgkmcnt(0)" ::: "memory");
    __builtin_amdgcn_s_setprio(1);
#pragma unroll
    for (int kh = 0; kh < 2; ++kh)
#pragma unroll
      for (int mi = 0; mi < 4; ++mi)
#pragma unroll
        for (int ni = 0; ni < 2; ++ni)
          acc[mi][ni + 2] = __builtin_amdgcn_mfma_f32_16x16x32_bf16(
              afl[kh][mi], bf23[kh][ni], acc[mi][ni + 2], 0, 0, 0);
    __builtin_amdgcn_s_setprio(0);
    __builtin_amdgcn_s_barrier();

    // ---- ph3: dsr af_hi(8); stage B0(t+2); q3 = mi4-7 x ni2-3
#pragma unroll
    for (int kh = 0; kh < 2; ++kh)
#pragma unroll
      for (int mi = 0; mi < 4; ++mi)
        afh[kh][mi] = *(const short8*)
            &Ah[((mi + 4) * 16 + frr) * 64 + ((kh * 32 + frk) ^ swz)];
    if (t + 2 < NT)
      stage_half(Bb + (size_t)(t + 2) * 64, K, LDS[t & 1][2], tid);
    FENCE();
    __builtin_amdgcn_s_barrier();
    asm volatile("s_waitcnt lgkmcnt(0)" ::: "memory");
    __builtin_amdgcn_s_setprio(1);
#pragma unroll
    for (int kh = 0; kh < 2; ++kh)
#pragma unroll
      for (int mi = 0; mi < 4; ++mi)
#pragma unroll
        for (int ni = 0; ni < 2; ++ni)
          acc[mi + 4][ni + 2] = __builtin_amdgcn_mfma_f32_16x16x32_bf16(
              afh[kh][mi], bf23[kh][ni], acc[mi + 4][ni + 2], 0, 0, 0);
    __builtin_amdgcn_s_setprio(0);
    __builtin_amdgcn_s_barrier();

    // ---- ph4: no dsr (afh,bf01 reg-carried); stage B1(t+2); counted wait;
    //      q4 = mi4-7 x ni0-1
    if (t + 2 < NT) {
      stage_half(Bb + (size_t)128 * K + (t + 2) * 64, K, LDS[t & 1][3], tid);
      asm volatile("s_waitcnt vmcnt(4)" ::: "memory");
    } else {
      asm volatile("s_waitcnt vmcnt(0)" ::: "memory");
    }
    __builtin_amdgcn_s_barrier();
    __builtin_amdgcn_s_setprio(1);
#pragma unroll
    for (int kh = 0; kh < 2; ++kh)
#pragma unroll
      for (int mi = 0; mi < 4; ++mi)
#pragma unroll
        for (int ni = 0; ni < 2; ++ni)
          acc[mi + 4][ni] = __builtin_amdgcn_mfma_f32_16x16x32_bf16(
              afh[kh][mi], bf01[kh][ni], acc[mi + 4][ni], 0, 0, 0);
    __builtin_amdgcn_s_setprio(0);
    __builtin_amdgcn_s_barrier();
    FENCE();
  }

  // epilogue: C/D layout col = lane&15, row = (lane>>4)*4 + r
  const int rb = (lane >> 4) * 4;
#pragma unroll
  for (int mi = 0; mi < 8; ++mi)
#pragma unroll
    for (int ni = 0; ni < 4; ++ni) {
      const floatx4 vv = acc[mi][ni];
      const int n = n0 + wc * 64 + ni * 16 + frr;
#pragma unroll
      for (int r = 0; r < 4; ++r) {
        const int m = m0 + wr * 128 + mi * 16 + rb + r;
        const size_t idx = (size_t)m * N + n;
        if (EPI == 1) {
          float s = 1.0f / (1.0f + __expf(-vv[r]));
          ((unsigned short*)Cout)[idx] = f2bs(s);
        } else {
          float g = bs2f(Gate[idx]);
          ((float*)Cout)[idx] = g * vv[r];
        }
      }
    }
}

// ---------- 128^2 / BK=64 GEMM core (r9-proven): 2-phase dbuf --------------
DEV void gemm128d(const unsigned short* __restrict__ A,
                  const unsigned short* __restrict__ Bw, const int K,
                  const int m0, const int n0, unsigned short* LDS,
                  floatx4 (&acc)[4][4], const int tid) {
  const int lane = tid & 63;
  const int w = tid >> 6;
  const int wr = w >> 1, wc = w & 1;
  const int frr = lane & 15;
  const int frk = (lane >> 4) * 8;
  const int aswz = (frr & 7) * 8;
  const int r_a = tid >> 3;                         // 0..31
  const int c_src = ((tid & 7) ^ (r_a & 7)) * 8;    // pre-swizzled col
  const unsigned short* Ag = A + (size_t)(m0 + r_a) * K + c_src;
  const unsigned short* Bg = Bw + (size_t)(n0 + r_a) * K + c_src;
  const int NT = K >> 6;

  {
    char* AsD = (char*)LDS + tid * 16;
    char* BsD = (char*)(LDS + 16384) + tid * 16;
#pragma unroll
    for (int i = 0; i < 4; ++i) {
      gload_lds16(Ag + (size_t)i * 32 * K, AsD + i * 4096);
      gload_lds16(Bg + (size_t)i * 32 * K, BsD + i * 4096);
    }
  }
  asm volatile("s_waitcnt vmcnt(0)" ::: "memory");
  __builtin_amdgcn_s_barrier();
  FENCE();

  int cur = 0;
  for (int t = 0; t < NT; ++t) {
    if (t + 1 < NT) {
      char* AsD = (char*)(LDS + (cur ^ 1) * 8192) + tid * 16;
      char* BsD = (char*)(LDS + 16384 + (cur ^ 1) * 8192) + tid * 16;
      const int k0 = (t + 1) * 64;
#pragma unroll
      for (int i = 0; i < 4; ++i) {
        gload_lds16(Ag + (size_t)i * 32 * K + k0, AsD + i * 4096);
        gload_lds16(Bg + (size_t)i * 32 * K + k0, BsD + i * 4096);
      }
    }
    const unsigned short* Asb = LDS + cur * 8192;
    const unsigned short* Bsb = LDS + 16384 + cur * 8192;
#pragma unroll
    for (int kk = 0; kk < 2; ++kk) {
      short8 a[4], b[4];
#pragma unroll
      for (int mi = 0; mi < 4; ++mi)
        a[mi] = *(const short8*)
            &Asb[(wr * 64 + mi * 16 + frr) * 64 + ((kk * 32 + frk) ^ aswz)];
#pragma unroll
      for (int ni = 0; ni < 4; ++ni)
        b[ni] = *(const short8*)
            &Bsb[(wc * 64 + ni * 16 + frr) * 64 + ((kk * 32 + frk) ^ aswz)];
#pragma unroll
      for (int mi = 0; mi < 4; ++mi)
#pragma unroll
        for (int ni = 0; ni < 4; ++ni)
          acc[mi][ni] = __builtin_amdgcn_mfma_f32_16x16x32_bf16(
              a[mi], b[ni], acc[mi][ni], 0, 0, 0);
    }
    if (t + 1 < NT) {
      asm volatile("s_waitcnt vmcnt(0)" ::: "memory");
      __builtin_amdgcn_s_barrier();
      FENCE();
    }
    cur ^= 1;
  }
  __syncthreads();
}

// ---------- fused q-path (r9-proven): q=X@qw^T -> L2-norm -> @S -> rmsnorm -
__global__ __launch_bounds__(256, 2) void k_fused_q(
    const unsigned short* __restrict__ X, const unsigned short* __restrict__ qwb,
    const unsigned short* __restrict__ St, const float* __restrict__ vnw,
    unsigned short* __restrict__ Ob) {
  __shared__ unsigned short LD[4 * 128 * 64];  // 64 KB; qt overlays [0,16K)
  const int tid = threadIdx.x;
  const int lane = tid & 63;
  const int w = tid >> 6;
  const int wr = w >> 1, wc = w & 1;
  const int bid = blockIdx.x;               // nwg = 1024
  const int v = (bid & 7) * 128 + (bid >> 3);
  const int m0 = (v >> 2) * 128;
  const int n0 = (v & 3) * 128;             // q-dim base; heads h0..h0+3
  const int h0 = n0 >> 5;
  const int batch = m0 >> 13;               // 8192 tokens per batch

  floatx4 acc[4][4];
#pragma unroll
  for (int i = 0; i < 4; ++i)
#pragma unroll
    for (int j = 0; j < 4; ++j) acc[i][j] = (floatx4){0.f, 0.f, 0.f, 0.f};

  gemm128d(X, qwb, Hdim, m0, n0, LD, acc, tid);

  const int rb = (lane >> 4) * 4;
  const int frr = lane & 15;
#pragma unroll
  for (int mi = 0; mi < 4; ++mi)
#pragma unroll
    for (int p = 0; p < 2; ++p) {
#pragma unroll
      for (int r = 0; r < 4; ++r) {
        float v0 = acc[mi][2 * p][r], v1 = acc[mi][2 * p + 1][r];
        float ss = v0 * v0 + v1 * v1;
        ss += __shfl_xor(ss, 1, 64);
        ss += __shfl_xor(ss, 2, 64);
        ss += __shfl_xor(ss, 4, 64);
        ss += __shfl_xor(ss, 8, 64);
        const float inv = 1.0f / fmaxf(sqrtf(ss), 1e-12f);
        const int m = wr * 64 + mi * 16 + rb + r;
        const int c0 = wc * 64 + p * 32 + frr;
        const int sw = (m & 7) * 8;
        LD[m * 128 + (c0 ^ sw)] = f2bs(v0 * inv);
        LD[m * 128 + ((c0 + 16) ^ sw)] = f2bs(v1 * inv);
      }
    }
  __syncthreads();

  const int frk = (lane >> 4) * 8;
  float wv[4];
#pragma unroll
  for (int ni = 0; ni < 4; ++ni) wv[ni] = vnw[ni * 16 + frr];

#pragma unroll
  for (int hh = 0; hh < 4; ++hh) {
    const unsigned short* Sp = St + (size_t)(batch * NH + h0 + hh) * (HV * HK);
    short8 bfr[4];
#pragma unroll
    for (int ni = 0; ni < 4; ++ni)
      bfr[ni] = *(const short8*)&Sp[(ni * 16 + frr) * HK + frk];
    floatx4 acc2[2][4];
#pragma unroll
    for (int i = 0; i < 2; ++i)
#pragma unroll
      for (int j = 0; j < 4; ++j) acc2[i][j] = (floatx4){0.f, 0.f, 0.f, 0.f};
    short8 af[2];
#pragma unroll
    for (int mi2 = 0; mi2 < 2; ++mi2) {
      const int m = w * 32 + mi2 * 16 + frr;
      af[mi2] = *(const short8*)&LD[m * 128 + ((hh * 32 + frk) ^ ((m & 7) * 8))];
    }
#pragma unroll
    for (int mi2 = 0; mi2 < 2; ++mi2)
#pragma unroll
      for (int ni = 0; ni < 4; ++ni)
        acc2[mi2][ni] = __builtin_amdgcn_mfma_f32_16x16x32_bf16(
            af[mi2], bfr[ni], acc2[mi2][ni], 0, 0, 0);

#pragma unroll
    for (int mi2 = 0; mi2 < 2; ++mi2)
#pragma unroll
      for (int r = 0; r < 4; ++r) {
        float ss2 = 0.f;
#pragma unroll
        for (int ni = 0; ni < 4; ++ni) ss2 += acc2[mi2][ni][r] * acc2[mi2][ni][r];
        ss2 += __shfl_xor(ss2, 1, 64);
        ss2 += __shfl_xor(ss2, 2, 64);
        ss2 += __shfl_xor(ss2, 4, 64);
        ss2 += __shfl_xor(ss2, 8, 64);
        const float sc = rsqrtf(ss2 * (1.0f / HV) + 1e-5f);
        const int m = m0 + w * 32 + mi2 * 16 + rb + r;
        unsigned short* Op = Ob + (size_t)m * Hdim + (h0 + hh) * HV;
#pragma unroll
        for (int ni = 0; ni < 4; ++ni)
          Op[ni * 16 + frr] = f2bs(acc2[mi2][ni][r] * sc * wv[ni]);
      }
  }
}

extern "C" void kernel_launch(void* const* d_in, const int* in_sizes, int n_in,
                              void* d_out, int out_size, void* d_ws, size_t ws_size,
                              hipStream_t stream) {
  const float* hs = (const float*)d_in[0];
  const float* Srec = (const float*)d_in[1];
  const float* nw = (const float*)d_in[2];
  const float* qw = (const float*)d_in[3];
  const float* vnw = (const float*)d_in[4];
  const float* ow = (const float*)d_in[5];
  const float* gw = (const float*)d_in[6];

  char* ws = (char*)d_ws;
  unsigned short* X = (unsigned short*)(ws);                          // 64 MB bf16 [M,H]
  unsigned short* Ob = (unsigned short*)(ws + ((size_t)64 << 20));    // 64 MB bf16 [M,VD]
  unsigned short* Gs = (unsigned short*)(ws + ((size_t)128 << 20));   // 64 MB bf16 [M,H]
  unsigned short* qwb = (unsigned short*)(ws + ((size_t)192 << 20));  // 1 MB
  unsigned short* gwb = (unsigned short*)(ws + ((size_t)193 << 20));  // 2 MB
  unsigned short* owb = (unsigned short*)(ws + ((size_t)195 << 20));  // 2 MB
  unsigned short* Stb = (unsigned short*)(ws + ((size_t)197 << 20));  // 256 KB

  // weights f32 -> bf16 (+ S transpose)
  k_cvt<<<(KDim * Hdim / 4 + 255) / 256, 256, 0, stream>>>(
      (const float4*)qw, (uint2v*)qwb, KDim * Hdim / 4);
  k_cvt<<<(Hdim * Hdim / 4 + 255) / 256, 256, 0, stream>>>(
      (const float4*)gw, (uint2v*)gwb, Hdim * Hdim / 4);
  k_cvt<<<(Hdim * Hdim / 4 + 255) / 256, 256, 0, stream>>>(
      (const float4*)ow, (uint2v*)owb, Hdim * Hdim / 4);
  k_cvts<<<(4 * NH * HV * HK + 255) / 256, 256, 0, stream>>>(Srec, Stb);

  // x = rmsnorm(hidden) -> bf16
  k_rmsnorm<<<Mtok, 256, 0, stream>>>(hs, nw, (uint2v*)X);

  // fused q path -> Ob
  k_fused_q<<<(Mtok / 128) * (KDim / 128), 256, 0, stream>>>(
      X, qwb, Stb, vnw, Ob);

  // Gs = sigmoid(X @ gate_w^T)  (256^2 8-phase)
  k_gemm256p<1><<<(Mtok / 256) * (Hdim / 256), 512, 0, stream>>>(
      X, gwb, Gs, nullptr, Hdim, Hdim);

  // out = Gs * (Ob @ o_w^T) -> f32 d_out  (256^2 8-phase)
  k_gemm256p<2><<<(Mtok / 256) * (Hdim / 256), 512, 0, stream>>>(
      Ob, owb, (float*)d_out, Gs, Hdim, Hdim);
}

// Round 14
// 280.292 us; speedup vs baseline: 1.6342x; 1.0517x over previous
//
#include <hip/hip_runtime.h>
#include <hip/hip_bf16.h>
#include <stdint.h>

typedef __attribute__((ext_vector_type(8))) short short8;
typedef __attribute__((ext_vector_type(4))) float floatx4;
typedef __attribute__((ext_vector_type(2))) unsigned int uint2v;

#define DEV static __device__ __forceinline__
#define FENCE() asm volatile("" ::: "memory")

DEV unsigned short f2bs(float f) {           // f32 -> bf16 bits, RNE
  union { float f; unsigned u; } v; v.f = f;
  unsigned u = v.u;
  u += 0x7fffu + ((u >> 16) & 1u);
  return (unsigned short)(u >> 16);
}
DEV float bs2f(unsigned short s) {
  union { unsigned u; float f; } v; v.u = ((unsigned)s) << 16;
  return v.f;
}
DEV unsigned pack2(float a, float b) {
  return (unsigned)f2bs(a) | ((unsigned)f2bs(b) << 16);
}

DEV void gload_lds16(const void* g, void* l) {
  __builtin_amdgcn_global_load_lds(
      (const __attribute__((address_space(1))) void*)g,
      (__attribute__((address_space(3))) void*)l, 16, 0, 0);
}

static constexpr int Hdim = 1024;
static constexpr int KDim = 512;
static constexpr int NH = 16;
static constexpr int HK = 32;
static constexpr int HV = 64;
static constexpr int Mtok = 4 * 8192;

// ---------- f32 -> bf16 convert (weights) ----------
__global__ __launch_bounds__(256) void k_cvt(const float4* __restrict__ in,
                                             uint2v* __restrict__ out, int n4) {
  int i = blockIdx.x * 256 + threadIdx.x;
  if (i >= n4) return;
  float4 v = in[i];
  uint2v o;
  o.x = pack2(v.x, v.y);
  o.y = pack2(v.z, v.w);
  out[i] = o;
}

// ---------- S -> S^T bf16:  St[b][h][v][k] = S[b][h][k][v] ----------
__global__ __launch_bounds__(256) void k_cvts(const float* __restrict__ S,
                                              unsigned short* __restrict__ St) {
  int i = blockIdx.x * 256 + threadIdx.x;      // over out idx, 4*16*64*32
  if (i >= 4 * NH * HV * HK) return;
  int k = i & 31, v = (i >> 5) & 63, bh = i >> 11;
  St[i] = f2bs(S[(size_t)(bh * HK + k) * HV + v]);
}

// ---------- rmsnorm(hidden) -> X bf16 ----------
__global__ __launch_bounds__(256) void k_rmsnorm(const float* __restrict__ hs,
                                                 const float* __restrict__ nw,
                                                 uint2v* __restrict__ X) {
  const int token = blockIdx.x;
  const int tid = threadIdx.x;
  float4 h = ((const float4*)(hs + (size_t)token * Hdim))[tid];
  float ss = h.x * h.x + h.y * h.y + h.z * h.z + h.w * h.w;
#pragma unroll
  for (int off = 32; off > 0; off >>= 1) ss += __shfl_down(ss, off, 64);
  __shared__ float red[4];
  const int lane = tid & 63, wid = tid >> 6;
  if (lane == 0) red[wid] = ss;
  __syncthreads();
  float tot = red[0] + red[1] + red[2] + red[3];
  float sc = rsqrtf(tot * (1.0f / Hdim) + 1e-5f);
  float4 w = ((const float4*)nw)[tid];
  uint2v o;
  o.x = pack2(h.x * sc * w.x, h.y * sc * w.y);
  o.y = pack2(h.z * sc * w.z, h.w * sc * w.w);
  X[(size_t)token * 256 + tid] = o;
}

// ---------- 128^2 / BK=32 GEMM core: 2-phase dbuf, 32 KB LDS ----------------
// Row stride is 64 B (32 shorts) -> 16-lane b128 reads span only 16 banks.
// Swizzle: stored chunk = chunk ^ ((row>>1)&3)  (chunk = 16B unit of 4/row).
// Read XOR ((frr>>1)&3)*8 -> 8 rows hit 8 distinct 16B slots, 16 rows = 2-way
// (free, m136). (row+64)>>1 === row>>1 (mod 4) so one source swizzle serves
// both gload_lds instrs. Write side: linear dest + pre-swizzled global col.
// LDS layout (shorts): As0 [0,4K) As1 [4K,8K) Bs0 [8K,12K) Bs1 [12K,16K).
DEV void gemm128d32(const unsigned short* __restrict__ A,
                    const unsigned short* __restrict__ Bw, const int K,
                    const int m0, const int n0, unsigned short* LDS,
                    floatx4 (&acc)[4][4], const int tid) {
  const int lane = tid & 63;
  const int w = tid >> 6;
  const int wr = w >> 1, wc = w & 1;
  const int frr = lane & 15;
  const int frk = (lane >> 4) * 8;
  const int aswz = ((frr >> 1) & 3) * 8;
  const int r_a = tid >> 2;                              // 0..63
  const int c_src = ((tid & 3) ^ ((r_a >> 1) & 3)) * 8;  // pre-swizzled col
  const unsigned short* Ag = A + (size_t)(m0 + r_a) * K + c_src;
  const unsigned short* Bg = Bw + (size_t)(n0 + r_a) * K + c_src;
  const int NT = K >> 5;

  // prologue: tile 0 -> slot 0
  {
    char* AsD = (char*)LDS + tid * 16;
    char* BsD = (char*)LDS + 16384 + tid * 16;
    gload_lds16(Ag, AsD);
    gload_lds16(Ag + (size_t)64 * K, AsD + 4096);
    gload_lds16(Bg, BsD);
    gload_lds16(Bg + (size_t)64 * K, BsD + 4096);
  }
  asm volatile("s_waitcnt vmcnt(0)" ::: "memory");
  __builtin_amdgcn_s_barrier();
  FENCE();

  int cur = 0;
  for (int t = 0; t < NT; ++t) {
    // issue next-tile stage into the other slot (in flight during compute)
    if (t + 1 < NT) {
      char* AsD = (char*)LDS + (cur ^ 1) * 8192 + tid * 16;
      char* BsD = (char*)LDS + 16384 + (cur ^ 1) * 8192 + tid * 16;
      const int k0 = (t + 1) * 32;
      gload_lds16(Ag + k0, AsD);
      gload_lds16(Ag + (size_t)64 * K + k0, AsD + 4096);
      gload_lds16(Bg + k0, BsD);
      gload_lds16(Bg + (size_t)64 * K + k0, BsD + 4096);
    }
    // compute current slot (one kk: K-step = 32)
    const unsigned short* Asb = LDS + cur * 4096;
    const unsigned short* Bsb = LDS + 8192 + cur * 4096;
    short8 a[4], b[4];
#pragma unroll
    for (int mi = 0; mi < 4; ++mi)
      a[mi] = *(const short8*)
          &Asb[(wr * 64 + mi * 16 + frr) * 32 + (frk ^ aswz)];
#pragma unroll
    for (int ni = 0; ni < 4; ++ni)
      b[ni] = *(const short8*)
          &Bsb[(wc * 64 + ni * 16 + frr) * 32 + (frk ^ aswz)];
#pragma unroll
    for (int mi = 0; mi < 4; ++mi)
#pragma unroll
      for (int ni = 0; ni < 4; ++ni)
        acc[mi][ni] = __builtin_amdgcn_mfma_f32_16x16x32_bf16(
            a[mi], b[ni], acc[mi][ni], 0, 0, 0);
    // next tile landed; flip
    if (t + 1 < NT) {
      asm volatile("s_waitcnt vmcnt(0)" ::: "memory");
      __builtin_amdgcn_s_barrier();
      FENCE();
    }
    cur ^= 1;
  }
  __syncthreads();
}

// ---------- fused gate+o:  out = sigmoid(X@gw^T) * (Ob@ow^T), f32 ----------
// 1D grid 2048; XCD-chunked, m-major within chunk (A-tile L2-resident).
// 32 KB LDS + (256,3) -> 3 blocks/CU co-resident fill barrier drains.
__global__ __launch_bounds__(256, 3) void k_fused_go(
    const unsigned short* __restrict__ X, const unsigned short* __restrict__ Ob,
    const unsigned short* __restrict__ gwb,
    const unsigned short* __restrict__ owb, float* __restrict__ out) {
  __shared__ unsigned short LDS[4 * 128 * 32];   // 32 KB (2 slots x A,B)
  const int tid = threadIdx.x;
  const int lane = tid & 63;
  const int w = tid >> 6;
  const int wr = w >> 1, wc = w & 1;
  const int bid = blockIdx.x;               // nwg = 2048 (multiple of 8)
  const int v = (bid & 7) * 256 + (bid >> 3);
  const int m0 = (v >> 3) * 128;            // m-major within XCD chunk
  const int n0 = (v & 7) * 128;

  floatx4 acc[4][4];
#pragma unroll
  for (int i = 0; i < 4; ++i)
#pragma unroll
    for (int j = 0; j < 4; ++j) acc[i][j] = (floatx4){0.f, 0.f, 0.f, 0.f};

  // pass 1: gate
  gemm128d32(X, gwb, Hdim, m0, n0, LDS, acc, tid);

  // sigmoid -> packed bf16 stash
  unsigned pg[4][4][2];
#pragma unroll
  for (int mi = 0; mi < 4; ++mi)
#pragma unroll
    for (int ni = 0; ni < 4; ++ni) {
      float s0 = 1.0f / (1.0f + __expf(-acc[mi][ni][0]));
      float s1 = 1.0f / (1.0f + __expf(-acc[mi][ni][1]));
      float s2 = 1.0f / (1.0f + __expf(-acc[mi][ni][2]));
      float s3 = 1.0f / (1.0f + __expf(-acc[mi][ni][3]));
      pg[mi][ni][0] = pack2(s0, s1);
      pg[mi][ni][1] = pack2(s2, s3);
      acc[mi][ni] = (floatx4){0.f, 0.f, 0.f, 0.f};
    }

  // pass 2: o-proj
  gemm128d32(Ob, owb, Hdim, m0, n0, LDS, acc, tid);

  // epilogue: C/D layout col = lane&15, row = (lane>>4)*4 + r
  const int rb = (lane >> 4) * 4;
#pragma unroll
  for (int mi = 0; mi < 4; ++mi)
#pragma unroll
    for (int ni = 0; ni < 4; ++ni) {
      const int n = n0 + wc * 64 + ni * 16 + (lane & 15);
#pragma unroll
      for (int r = 0; r < 4; ++r) {
        const int m = m0 + wr * 64 + mi * 16 + rb + r;
        float g = bs2f((unsigned short)(pg[mi][ni][r >> 1] >> ((r & 1) * 16)));
        out[(size_t)m * Hdim + n] = g * acc[mi][ni][r];
      }
    }
}

// ---------- 128^2 / BK=64 GEMM core (r9-proven, unchanged) -----------------
DEV void gemm128d(const unsigned short* __restrict__ A,
                  const unsigned short* __restrict__ Bw, const int K,
                  const int m0, const int n0, unsigned short* LDS,
                  floatx4 (&acc)[4][4], const int tid) {
  const int lane = tid & 63;
  const int w = tid >> 6;
  const int wr = w >> 1, wc = w & 1;
  const int frr = lane & 15;
  const int frk = (lane >> 4) * 8;
  const int aswz = (frr & 7) * 8;
  const int r_a = tid >> 3;                         // 0..31
  const int c_src = ((tid & 7) ^ (r_a & 7)) * 8;    // pre-swizzled col
  const unsigned short* Ag = A + (size_t)(m0 + r_a) * K + c_src;
  const unsigned short* Bg = Bw + (size_t)(n0 + r_a) * K + c_src;
  const int NT = K >> 6;

  {
    char* AsD = (char*)LDS + tid * 16;
    char* BsD = (char*)(LDS + 16384) + tid * 16;
#pragma unroll
    for (int i = 0; i < 4; ++i) {
      gload_lds16(Ag + (size_t)i * 32 * K, AsD + i * 4096);
      gload_lds16(Bg + (size_t)i * 32 * K, BsD + i * 4096);
    }
  }
  asm volatile("s_waitcnt vmcnt(0)" ::: "memory");
  __builtin_amdgcn_s_barrier();
  FENCE();

  int cur = 0;
  for (int t = 0; t < NT; ++t) {
    if (t + 1 < NT) {
      char* AsD = (char*)(LDS + (cur ^ 1) * 8192) + tid * 16;
      char* BsD = (char*)(LDS + 16384 + (cur ^ 1) * 8192) + tid * 16;
      const int k0 = (t + 1) * 64;
#pragma unroll
      for (int i = 0; i < 4; ++i) {
        gload_lds16(Ag + (size_t)i * 32 * K + k0, AsD + i * 4096);
        gload_lds16(Bg + (size_t)i * 32 * K + k0, BsD + i * 4096);
      }
    }
    const unsigned short* Asb = LDS + cur * 8192;
    const unsigned short* Bsb = LDS + 16384 + cur * 8192;
#pragma unroll
    for (int kk = 0; kk < 2; ++kk) {
      short8 a[4], b[4];
#pragma unroll
      for (int mi = 0; mi < 4; ++mi)
        a[mi] = *(const short8*)
            &Asb[(wr * 64 + mi * 16 + frr) * 64 + ((kk * 32 + frk) ^ aswz)];
#pragma unroll
      for (int ni = 0; ni < 4; ++ni)
        b[ni] = *(const short8*)
            &Bsb[(wc * 64 + ni * 16 + frr) * 64 + ((kk * 32 + frk) ^ aswz)];
#pragma unroll
      for (int mi = 0; mi < 4; ++mi)
#pragma unroll
        for (int ni = 0; ni < 4; ++ni)
          acc[mi][ni] = __builtin_amdgcn_mfma_f32_16x16x32_bf16(
              a[mi], b[ni], acc[mi][ni], 0, 0, 0);
    }
    if (t + 1 < NT) {
      asm volatile("s_waitcnt vmcnt(0)" ::: "memory");
      __builtin_amdgcn_s_barrier();
      FENCE();
    }
    cur ^= 1;
  }
  __syncthreads();
}

// ---------- fused q-path (r9-proven): q=X@qw^T -> L2-norm -> @S -> rmsnorm -
__global__ __launch_bounds__(256, 2) void k_fused_q(
    const unsigned short* __restrict__ X, const unsigned short* __restrict__ qwb,
    const unsigned short* __restrict__ St, const float* __restrict__ vnw,
    unsigned short* __restrict__ Ob) {
  __shared__ unsigned short LD[4 * 128 * 64];  // 64 KB; qt overlays [0,16K)
  const int tid = threadIdx.x;
  const int lane = tid & 63;
  const int w = tid >> 6;
  const int wr = w >> 1, wc = w & 1;
  const int bid = blockIdx.x;               // nwg = 1024
  const int v = (bid & 7) * 128 + (bid >> 3);
  const int m0 = (v >> 2) * 128;
  const int n0 = (v & 3) * 128;             // q-dim base; heads h0..h0+3
  const int h0 = n0 >> 5;
  const int batch = m0 >> 13;               // 8192 tokens per batch

  floatx4 acc[4][4];
#pragma unroll
  for (int i = 0; i < 4; ++i)
#pragma unroll
    for (int j = 0; j < 4; ++j) acc[i][j] = (floatx4){0.f, 0.f, 0.f, 0.f};

  gemm128d(X, qwb, Hdim, m0, n0, LD, acc, tid);

  const int rb = (lane >> 4) * 4;
  const int frr = lane & 15;
#pragma unroll
  for (int mi = 0; mi < 4; ++mi)
#pragma unroll
    for (int p = 0; p < 2; ++p) {
#pragma unroll
      for (int r = 0; r < 4; ++r) {
        float v0 = acc[mi][2 * p][r], v1 = acc[mi][2 * p + 1][r];
        float ss = v0 * v0 + v1 * v1;
        ss += __shfl_xor(ss, 1, 64);
        ss += __shfl_xor(ss, 2, 64);
        ss += __shfl_xor(ss, 4, 64);
        ss += __shfl_xor(ss, 8, 64);
        const float inv = 1.0f / fmaxf(sqrtf(ss), 1e-12f);
        const int m = wr * 64 + mi * 16 + rb + r;
        const int c0 = wc * 64 + p * 32 + frr;
        const int sw = (m & 7) * 8;
        LD[m * 128 + (c0 ^ sw)] = f2bs(v0 * inv);
        LD[m * 128 + ((c0 + 16) ^ sw)] = f2bs(v1 * inv);
      }
    }
  __syncthreads();

  const int frk = (lane >> 4) * 8;
  float wv[4];
#pragma unroll
  for (int ni = 0; ni < 4; ++ni) wv[ni] = vnw[ni * 16 + frr];

#pragma unroll
  for (int hh = 0; hh < 4; ++hh) {
    const unsigned short* Sp = St + (size_t)(batch * NH + h0 + hh) * (HV * HK);
    short8 bfr[4];
#pragma unroll
    for (int ni = 0; ni < 4; ++ni)
      bfr[ni] = *(const short8*)&Sp[(ni * 16 + frr) * HK + frk];
    floatx4 acc2[2][4];
#pragma unroll
    for (int i = 0; i < 2; ++i)
#pragma unroll
      for (int j = 0; j < 4; ++j) acc2[i][j] = (floatx4){0.f, 0.f, 0.f, 0.f};
    short8 af[2];
#pragma unroll
    for (int mi2 = 0; mi2 < 2; ++mi2) {
      const int m = w * 32 + mi2 * 16 + frr;
      af[mi2] = *(const short8*)&LD[m * 128 + ((hh * 32 + frk) ^ ((m & 7) * 8))];
    }
#pragma unroll
    for (int mi2 = 0; mi2 < 2; ++mi2)
#pragma unroll
      for (int ni = 0; ni < 4; ++ni)
        acc2[mi2][ni] = __builtin_amdgcn_mfma_f32_16x16x32_bf16(
            af[mi2], bfr[ni], acc2[mi2][ni], 0, 0, 0);

#pragma unroll
    for (int mi2 = 0; mi2 < 2; ++mi2)
#pragma unroll
      for (int r = 0; r < 4; ++r) {
        float ss2 = 0.f;
#pragma unroll
        for (int ni = 0; ni < 4; ++ni) ss2 += acc2[mi2][ni][r] * acc2[mi2][ni][r];
        ss2 += __shfl_xor(ss2, 1, 64);
        ss2 += __shfl_xor(ss2, 2, 64);
        ss2 += __shfl_xor(ss2, 4, 64);
        ss2 += __shfl_xor(ss2, 8, 64);
        const float sc = rsqrtf(ss2 * (1.0f / HV) + 1e-5f);
        const int m = m0 + w * 32 + mi2 * 16 + rb + r;
        unsigned short* Op = Ob + (size_t)m * Hdim + (h0 + hh) * HV;
#pragma unroll
        for (int ni = 0; ni < 4; ++ni)
          Op[ni * 16 + frr] = f2bs(acc2[mi2][ni][r] * sc * wv[ni]);
      }
  }
}

extern "C" void kernel_launch(void* const* d_in, const int* in_sizes, int n_in,
                              void* d_out, int out_size, void* d_ws, size_t ws_size,
                              hipStream_t stream) {
  const float* hs = (const float*)d_in[0];
  const float* Srec = (const float*)d_in[1];
  const float* nw = (const float*)d_in[2];
  const float* qw = (const float*)d_in[3];
  const float* vnw = (const float*)d_in[4];
  const float* ow = (const float*)d_in[5];
  const float* gw = (const float*)d_in[6];

  char* ws = (char*)d_ws;
  unsigned short* X = (unsigned short*)(ws);                          // 64 MB bf16 [M,H]
  unsigned short* Ob = (unsigned short*)(ws + ((size_t)64 << 20));    // 64 MB bf16 [M,VD]
  unsigned short* qwb = (unsigned short*)(ws + ((size_t)128 << 20));  // 1 MB
  unsigned short* gwb = (unsigned short*)(ws + ((size_t)129 << 20));  // 2 MB
  unsigned short* owb = (unsigned short*)(ws + ((size_t)131 << 20));  // 2 MB
  unsigned short* Stb = (unsigned short*)(ws + ((size_t)133 << 20));  // 256 KB

  // weights f32 -> bf16 (+ S transpose)
  k_cvt<<<(KDim * Hdim / 4 + 255) / 256, 256, 0, stream>>>(
      (const float4*)qw, (uint2v*)qwb, KDim * Hdim / 4);
  k_cvt<<<(Hdim * Hdim / 4 + 255) / 256, 256, 0, stream>>>(
      (const float4*)gw, (uint2v*)gwb, Hdim * Hdim / 4);
  k_cvt<<<(Hdim * Hdim / 4 + 255) / 256, 256, 0, stream>>>(
      (const float4*)ow, (uint2v*)owb, Hdim * Hdim / 4);
  k_cvts<<<(4 * NH * HV * HK + 255) / 256, 256, 0, stream>>>(Srec, Stb);

  // x = rmsnorm(hidden) -> bf16
  k_rmsnorm<<<Mtok, 256, 0, stream>>>(hs, nw, (uint2v*)X);

  // fused q path -> Ob
  k_fused_q<<<(Mtok / 128) * (KDim / 128), 256, 0, stream>>>(
      X, qwb, Stb, vnw, Ob);

  // fused gate+o -> d_out f32
  k_fused_go<<<(Mtok / 128) * (Hdim / 128), 256, 0, stream>>>(
      X, Ob, gwb, owb, (float*)d_out);
}

// Round 16
// 259.115 us; speedup vs baseline: 1.7678x; 1.0817x over previous
//
#include <hip/hip_runtime.h>
#include <hip/hip_bf16.h>
#include <stdint.h>

typedef __attribute__((ext_vector_type(8))) short short8;
typedef __attribute__((ext_vector_type(4))) float floatx4;
typedef __attribute__((ext_vector_type(2))) unsigned int uint2v;

#define DEV static __device__ __forceinline__
#define FENCE() asm volatile("" ::: "memory")

DEV unsigned short f2bs(float f) {           // f32 -> bf16 bits, RNE
  union { float f; unsigned u; } v; v.f = f;
  unsigned u = v.u;
  u += 0x7fffu + ((u >> 16) & 1u);
  return (unsigned short)(u >> 16);
}
DEV float bs2f(unsigned short s) {
  union { unsigned u; float f; } v; v.u = ((unsigned)s) << 16;
  return v.f;
}
DEV unsigned pack2(float a, float b) {
  return (unsigned)f2bs(a) | ((unsigned)f2bs(b) << 16);
}

DEV void gload_lds16(const void* g, void* l) {
  __builtin_amdgcn_global_load_lds(
      (const __attribute__((address_space(1))) void*)g,
      (__attribute__((address_space(3))) void*)l, 16, 0, 0);
}

static constexpr int Hdim = 1024;
static constexpr int KDim = 512;
static constexpr int NH = 16;
static constexpr int HK = 32;
static constexpr int HV = 64;
static constexpr int Mtok = 4 * 8192;

// ---------- f32 -> bf16 convert (weights) ----------
__global__ __launch_bounds__(256) void k_cvt(const float4* __restrict__ in,
                                             uint2v* __restrict__ out, int n4) {
  int i = blockIdx.x * 256 + threadIdx.x;
  if (i >= n4) return;
  float4 v = in[i];
  uint2v o;
  o.x = pack2(v.x, v.y);
  o.y = pack2(v.z, v.w);
  out[i] = o;
}

// ---------- S -> S^T bf16:  St[b][h][v][k] = S[b][h][k][v] ----------
__global__ __launch_bounds__(256) void k_cvts(const float* __restrict__ S,
                                              unsigned short* __restrict__ St) {
  int i = blockIdx.x * 256 + threadIdx.x;      // over out idx, 4*16*64*32
  if (i >= 4 * NH * HV * HK) return;
  int k = i & 31, v = (i >> 5) & 63, bh = i >> 11;
  St[i] = f2bs(S[(size_t)(bh * HK + k) * HV + v]);
}

// ---------- rmsnorm(hidden) -> X bf16 ----------
__global__ __launch_bounds__(256) void k_rmsnorm(const float* __restrict__ hs,
                                                 const float* __restrict__ nw,
                                                 uint2v* __restrict__ X) {
  const int token = blockIdx.x;
  const int tid = threadIdx.x;
  float4 h = ((const float4*)(hs + (size_t)token * Hdim))[tid];
  float ss = h.x * h.x + h.y * h.y + h.z * h.z + h.w * h.w;
#pragma unroll
  for (int off = 32; off > 0; off >>= 1) ss += __shfl_down(ss, off, 64);
  __shared__ float red[4];
  const int lane = tid & 63, wid = tid >> 6;
  if (lane == 0) red[wid] = ss;
  __syncthreads();
  float tot = red[0] + red[1] + red[2] + red[3];
  float sc = rsqrtf(tot * (1.0f / Hdim) + 1e-5f);
  float4 w = ((const float4*)nw)[tid];
  uint2v o;
  o.x = pack2(h.x * sc * w.x, h.y * sc * w.y);
  o.y = pack2(h.z * sc * w.z, h.w * sc * w.w);
  X[(size_t)token * 256 + tid] = o;
}

// ---------- 128^2 / BK=64 GEMM core (r9-proven): 2-phase dbuf --------------
// T2 swizzle both sides: linear gload_lds dest + pre-swizzled global source
// col; read XOR (frr&7)*8 (0-conflict verified r4/r5/r8/r9).
// LDS layout (shorts): As0 [0,8K) As1 [8K,16K) Bs0 [16K,24K) Bs1 [24K,32K).
// 2-phase: STAGE(t+1) issued BEFORE compute(t); one vmcnt(0)+barrier per
// K-step AFTER compute. Ends with __syncthreads (LDS reusable after).
DEV void gemm128d(const unsigned short* __restrict__ A,
                  const unsigned short* __restrict__ Bw, const int K,
                  const int m0, const int n0, unsigned short* LDS,
                  floatx4 (&acc)[4][4], const int tid) {
  const int lane = tid & 63;
  const int w = tid >> 6;
  const int wr = w >> 1, wc = w & 1;
  const int frr = lane & 15;
  const int frk = (lane >> 4) * 8;
  const int aswz = (frr & 7) * 8;
  const int r_a = tid >> 3;                         // 0..31
  const int c_src = ((tid & 7) ^ (r_a & 7)) * 8;    // pre-swizzled col
  const unsigned short* Ag = A + (size_t)(m0 + r_a) * K + c_src;
  const unsigned short* Bg = Bw + (size_t)(n0 + r_a) * K + c_src;
  const int NT = K >> 6;

  {
    char* AsD = (char*)LDS + tid * 16;
    char* BsD = (char*)(LDS + 16384) + tid * 16;
#pragma unroll
    for (int i = 0; i < 4; ++i) {
      gload_lds16(Ag + (size_t)i * 32 * K, AsD + i * 4096);
      gload_lds16(Bg + (size_t)i * 32 * K, BsD + i * 4096);
    }
  }
  asm volatile("s_waitcnt vmcnt(0)" ::: "memory");
  __builtin_amdgcn_s_barrier();
  FENCE();

  int cur = 0;
  for (int t = 0; t < NT; ++t) {
    if (t + 1 < NT) {
      char* AsD = (char*)(LDS + (cur ^ 1) * 8192) + tid * 16;
      char* BsD = (char*)(LDS + 16384 + (cur ^ 1) * 8192) + tid * 16;
      const int k0 = (t + 1) * 64;
#pragma unroll
      for (int i = 0; i < 4; ++i) {
        gload_lds16(Ag + (size_t)i * 32 * K + k0, AsD + i * 4096);
        gload_lds16(Bg + (size_t)i * 32 * K + k0, BsD + i * 4096);
      }
    }
    const unsigned short* Asb = LDS + cur * 8192;
    const unsigned short* Bsb = LDS + 16384 + cur * 8192;
#pragma unroll
    for (int kk = 0; kk < 2; ++kk) {
      short8 a[4], b[4];
#pragma unroll
      for (int mi = 0; mi < 4; ++mi)
        a[mi] = *(const short8*)
            &Asb[(wr * 64 + mi * 16 + frr) * 64 + ((kk * 32 + frk) ^ aswz)];
#pragma unroll
      for (int ni = 0; ni < 4; ++ni)
        b[ni] = *(const short8*)
            &Bsb[(wc * 64 + ni * 16 + frr) * 64 + ((kk * 32 + frk) ^ aswz)];
#pragma unroll
      for (int mi = 0; mi < 4; ++mi)
#pragma unroll
        for (int ni = 0; ni < 4; ++ni)
          acc[mi][ni] = __builtin_amdgcn_mfma_f32_16x16x32_bf16(
              a[mi], b[ni], acc[mi][ni], 0, 0, 0);
    }
    if (t + 1 < NT) {
      asm volatile("s_waitcnt vmcnt(0)" ::: "memory");
      __builtin_amdgcn_s_barrier();
      FENCE();
    }
    cur ^= 1;
  }
  __syncthreads();
}

// ---------- fused gate+o:  out = sigmoid(X@gw^T) * (Ob@ow^T), f32 ----------
// 1D grid 2048; XCD-chunked, m-major within chunk (A-tile L2-resident).
__global__ __launch_bounds__(256, 2) void k_fused_go(
    const unsigned short* __restrict__ X, const unsigned short* __restrict__ Ob,
    const unsigned short* __restrict__ gwb,
    const unsigned short* __restrict__ owb, float* __restrict__ out) {
  __shared__ unsigned short LDS[4 * 128 * 64];   // 64 KB (2 slots x A,B)
  const int tid = threadIdx.x;
  const int lane = tid & 63;
  const int w = tid >> 6;
  const int wr = w >> 1, wc = w & 1;
  const int bid = blockIdx.x;               // nwg = 2048 (multiple of 8)
  const int v = (bid & 7) * 256 + (bid >> 3);
  const int m0 = (v >> 3) * 128;            // m-major within XCD chunk
  const int n0 = (v & 7) * 128;

  floatx4 acc[4][4];
#pragma unroll
  for (int i = 0; i < 4; ++i)
#pragma unroll
    for (int j = 0; j < 4; ++j) acc[i][j] = (floatx4){0.f, 0.f, 0.f, 0.f};

  // pass 1: gate
  gemm128d(X, gwb, Hdim, m0, n0, LDS, acc, tid);

  // sigmoid -> packed bf16 stash
  unsigned pg[4][4][2];
#pragma unroll
  for (int mi = 0; mi < 4; ++mi)
#pragma unroll
    for (int ni = 0; ni < 4; ++ni) {
      float s0 = 1.0f / (1.0f + __expf(-acc[mi][ni][0]));
      float s1 = 1.0f / (1.0f + __expf(-acc[mi][ni][1]));
      float s2 = 1.0f / (1.0f + __expf(-acc[mi][ni][2]));
      float s3 = 1.0f / (1.0f + __expf(-acc[mi][ni][3]));
      pg[mi][ni][0] = pack2(s0, s1);
      pg[mi][ni][1] = pack2(s2, s3);
      acc[mi][ni] = (floatx4){0.f, 0.f, 0.f, 0.f};
    }

  // pass 2: o-proj
  gemm128d(Ob, owb, Hdim, m0, n0, LDS, acc, tid);

  // epilogue: C/D layout col = lane&15, row = (lane>>4)*4 + r
  const int rb = (lane >> 4) * 4;
#pragma unroll
  for (int mi = 0; mi < 4; ++mi)
#pragma unroll
    for (int ni = 0; ni < 4; ++ni) {
      const int n = n0 + wc * 64 + ni * 16 + (lane & 15);
#pragma unroll
      for (int r = 0; r < 4; ++r) {
        const int m = m0 + wr * 64 + mi * 16 + rb + r;
        float g = bs2f((unsigned short)(pg[mi][ni][r >> 1] >> ((r & 1) * 16)));
        out[(size_t)m * Hdim + n] = g * acc[mi][ni][r];
      }
    }
}

// ---------- fused q-path (r9-proven): q=X@qw^T -> L2-norm -> @S -> rmsnorm -
__global__ __launch_bounds__(256, 2) void k_fused_q(
    const unsigned short* __restrict__ X, const unsigned short* __restrict__ qwb,
    const unsigned short* __restrict__ St, const float* __restrict__ vnw,
    unsigned short* __restrict__ Ob) {
  __shared__ unsigned short LD[4 * 128 * 64];  // 64 KB; qt overlays [0,16K)
  const int tid = threadIdx.x;
  const int lane = tid & 63;
  const int w = tid >> 6;
  const int wr = w >> 1, wc = w & 1;
  const int bid = blockIdx.x;               // nwg = 1024
  const int v = (bid & 7) * 128 + (bid >> 3);
  const int m0 = (v >> 2) * 128;
  const int n0 = (v & 3) * 128;             // q-dim base; heads h0..h0+3
  const int h0 = n0 >> 5;
  const int batch = m0 >> 13;               // 8192 tokens per batch

  floatx4 acc[4][4];
#pragma unroll
  for (int i = 0; i < 4; ++i)
#pragma unroll
    for (int j = 0; j < 4; ++j) acc[i][j] = (floatx4){0.f, 0.f, 0.f, 0.f};

  gemm128d(X, qwb, Hdim, m0, n0, LD, acc, tid);

  const int rb = (lane >> 4) * 4;
  const int frr = lane & 15;
#pragma unroll
  for (int mi = 0; mi < 4; ++mi)
#pragma unroll
    for (int p = 0; p < 2; ++p) {
#pragma unroll
      for (int r = 0; r < 4; ++r) {
        float v0 = acc[mi][2 * p][r], v1 = acc[mi][2 * p + 1][r];
        float ss = v0 * v0 + v1 * v1;
        ss += __shfl_xor(ss, 1, 64);
        ss += __shfl_xor(ss, 2, 64);
        ss += __shfl_xor(ss, 4, 64);
        ss += __shfl_xor(ss, 8, 64);
        const float inv = 1.0f / fmaxf(sqrtf(ss), 1e-12f);
        const int m = wr * 64 + mi * 16 + rb + r;
        const int c0 = wc * 64 + p * 32 + frr;
        const int sw = (m & 7) * 8;
        LD[m * 128 + (c0 ^ sw)] = f2bs(v0 * inv);
        LD[m * 128 + ((c0 + 16) ^ sw)] = f2bs(v1 * inv);
      }
    }
  __syncthreads();

  const int frk = (lane >> 4) * 8;
  float wv[4];
#pragma unroll
  for (int ni = 0; ni < 4; ++ni) wv[ni] = vnw[ni * 16 + frr];

#pragma unroll
  for (int hh = 0; hh < 4; ++hh) {
    const unsigned short* Sp = St + (size_t)(batch * NH + h0 + hh) * (HV * HK);
    short8 bfr[4];
#pragma unroll
    for (int ni = 0; ni < 4; ++ni)
      bfr[ni] = *(const short8*)&Sp[(ni * 16 + frr) * HK + frk];
    floatx4 acc2[2][4];
#pragma unroll
    for (int i = 0; i < 2; ++i)
#pragma unroll
      for (int j = 0; j < 4; ++j) acc2[i][j] = (floatx4){0.f, 0.f, 0.f, 0.f};
    short8 af[2];
#pragma unroll
    for (int mi2 = 0; mi2 < 2; ++mi2) {
      const int m = w * 32 + mi2 * 16 + frr;
      af[mi2] = *(const short8*)&LD[m * 128 + ((hh * 32 + frk) ^ ((m & 7) * 8))];
    }
#pragma unroll
    for (int mi2 = 0; mi2 < 2; ++mi2)
#pragma unroll
      for (int ni = 0; ni < 4; ++ni)
        acc2[mi2][ni] = __builtin_amdgcn_mfma_f32_16x16x32_bf16(
            af[mi2], bfr[ni], acc2[mi2][ni], 0, 0, 0);

#pragma unroll
    for (int mi2 = 0; mi2 < 2; ++mi2)
#pragma unroll
      for (int r = 0; r < 4; ++r) {
        float ss2 = 0.f;
#pragma unroll
        for (int ni = 0; ni < 4; ++ni) ss2 += acc2[mi2][ni][r] * acc2[mi2][ni][r];
        ss2 += __shfl_xor(ss2, 1, 64);
        ss2 += __shfl_xor(ss2, 2, 64);
        ss2 += __shfl_xor(ss2, 4, 64);
        ss2 += __shfl_xor(ss2, 8, 64);
        const float sc = rsqrtf(ss2 * (1.0f / HV) + 1e-5f);
        const int m = m0 + w * 32 + mi2 * 16 + rb + r;
        unsigned short* Op = Ob + (size_t)m * Hdim + (h0 + hh) * HV;
#pragma unroll
        for (int ni = 0; ni < 4; ++ni)
          Op[ni * 16 + frr] = f2bs(acc2[mi2][ni][r] * sc * wv[ni]);
      }
  }
}

extern "C" void kernel_launch(void* const* d_in, const int* in_sizes, int n_in,
                              void* d_out, int out_size, void* d_ws, size_t ws_size,
                              hipStream_t stream) {
  const float* hs = (const float*)d_in[0];
  const float* Srec = (const float*)d_in[1];
  const float* nw = (const float*)d_in[2];
  const float* qw = (const float*)d_in[3];
  const float* vnw = (const float*)d_in[4];
  const float* ow = (const float*)d_in[5];
  const float* gw = (const float*)d_in[6];

  char* ws = (char*)d_ws;
  unsigned short* X = (unsigned short*)(ws);                          // 64 MB bf16 [M,H]
  unsigned short* Ob = (unsigned short*)(ws + ((size_t)64 << 20));    // 64 MB bf16 [M,VD]
  unsigned short* qwb = (unsigned short*)(ws + ((size_t)128 << 20));  // 1 MB
  unsigned short* gwb = (unsigned short*)(ws + ((size_t)129 << 20));  // 2 MB
  unsigned short* owb = (unsigned short*)(ws + ((size_t)131 << 20));  // 2 MB
  unsigned short* Stb = (unsigned short*)(ws + ((size_t)133 << 20));  // 256 KB

  // weights f32 -> bf16 (+ S transpose)
  k_cvt<<<(KDim * Hdim / 4 + 255) / 256, 256, 0, stream>>>(
      (const float4*)qw, (uint2v*)qwb, KDim * Hdim / 4);
  k_cvt<<<(Hdim * Hdim / 4 + 255) / 256, 256, 0, stream>>>(
      (const float4*)gw, (uint2v*)gwb, Hdim * Hdim / 4);
  k_cvt<<<(Hdim * Hdim / 4 + 255) / 256, 256, 0, stream>>>(
      (const float4*)ow, (uint2v*)owb, Hdim * Hdim / 4);
  k_cvts<<<(4 * NH * HV * HK + 255) / 256, 256, 0, stream>>>(Srec, Stb);

  // x = rmsnorm(hidden) -> bf16
  k_rmsnorm<<<Mtok, 256, 0, stream>>>(hs, nw, (uint2v*)X);

  // fused q path -> Ob
  k_fused_q<<<(Mtok / 128) * (KDim / 128), 256, 0, stream>>>(
      X, qwb, Stb, vnw, Ob);

  // fused gate+o -> d_out f32
  k_fused_go<<<(Mtok / 128) * (Hdim / 128), 256, 0, stream>>>(
      X, Ob, gwb, owb, (float*)d_out);
}

// Round 17
// 254.748 us; speedup vs baseline: 1.7981x; 1.0171x over previous
//
#include <hip/hip_runtime.h>
#include <hip/hip_bf16.h>
#include <stdint.h>

typedef __attribute__((ext_vector_type(8))) short short8;
typedef __attribute__((ext_vector_type(4))) float floatx4;
typedef __attribute__((ext_vector_type(2))) unsigned int uint2v;

#define DEV static __device__ __forceinline__
#define FENCE() asm volatile("" ::: "memory")

DEV unsigned short f2bs(float f) {           // f32 -> bf16 bits, RNE
  union { float f; unsigned u; } v; v.f = f;
  unsigned u = v.u;
  u += 0x7fffu + ((u >> 16) & 1u);
  return (unsigned short)(u >> 16);
}
DEV float bs2f(unsigned short s) {
  union { unsigned u; float f; } v; v.u = ((unsigned)s) << 16;
  return v.f;
}
DEV unsigned pack2(float a, float b) {
  return (unsigned)f2bs(a) | ((unsigned)f2bs(b) << 16);
}

DEV void gload_lds16(const void* g, void* l) {
  __builtin_amdgcn_global_load_lds(
      (const __attribute__((address_space(1))) void*)g,
      (__attribute__((address_space(3))) void*)l, 16, 0, 0);
}

static constexpr int Hdim = 1024;
static constexpr int KDim = 512;
static constexpr int NH = 16;
static constexpr int HK = 32;
static constexpr int HV = 64;
static constexpr int Mtok = 4 * 8192;

// ---------- merged prep: 3x weight f32->bf16 + S^T (one launch) ----------
// segments (in 256-thread units of work):
//   [0, 131072)           qw float4 cvt   (512*1024/4)
//   [131072, 393216)      gw float4 cvt   (1024*1024/4)
//   [393216, 655360)      ow float4 cvt   (1024*1024/4)
//   [655360, 786432)      St scalar transpose (4*16*64*32)
DEV void cvt4(const float4* __restrict__ in, uint2v* __restrict__ out, int i) {
  float4 v = in[i];
  uint2v o;
  o.x = pack2(v.x, v.y);
  o.y = pack2(v.z, v.w);
  out[i] = o;
}

__global__ __launch_bounds__(256) void k_prep(
    const float* __restrict__ qw, const float* __restrict__ gw,
    const float* __restrict__ ow, const float* __restrict__ S,
    uint2v* __restrict__ qwb, uint2v* __restrict__ gwb,
    uint2v* __restrict__ owb, unsigned short* __restrict__ St) {
  int i = blockIdx.x * 256 + threadIdx.x;
  if (i < 131072) {
    cvt4((const float4*)qw, qwb, i);
    return;
  }
  i -= 131072;
  if (i < 262144) {
    cvt4((const float4*)gw, gwb, i);
    return;
  }
  i -= 262144;
  if (i < 262144) {
    cvt4((const float4*)ow, owb, i);
    return;
  }
  i -= 262144;
  // S -> S^T bf16: St[b][h][v][k] = S[b][h][k][v]
  int k = i & 31, v = (i >> 5) & 63, bh = i >> 11;
  St[i] = f2bs(S[(size_t)(bh * HK + k) * HV + v]);
}

// ---------- rmsnorm(hidden) -> X bf16 : one WAVE per token ----------
// 4 tokens per 256-block; no LDS, no barrier; 6-step shuffle tree.
__global__ __launch_bounds__(256) void k_rmsnorm(const float* __restrict__ hs,
                                                 const float* __restrict__ nw,
                                                 uint2v* __restrict__ X) {
  const int lane = threadIdx.x & 63;
  const int token = blockIdx.x * 4 + (threadIdx.x >> 6);
  const float4* hp = (const float4*)(hs + (size_t)token * Hdim);
  float4 h[4];
  float ss = 0.f;
#pragma unroll
  for (int i = 0; i < 4; ++i) {
    h[i] = hp[i * 64 + lane];
    ss += h[i].x * h[i].x + h[i].y * h[i].y + h[i].z * h[i].z +
          h[i].w * h[i].w;
  }
#pragma unroll
  for (int off = 1; off < 64; off <<= 1) ss += __shfl_xor(ss, off, 64);
  const float sc = rsqrtf(ss * (1.0f / Hdim) + 1e-5f);
#pragma unroll
  for (int i = 0; i < 4; ++i) {
    float4 w = ((const float4*)nw)[i * 64 + lane];
    uint2v o;
    o.x = pack2(h[i].x * sc * w.x, h[i].y * sc * w.y);
    o.y = pack2(h[i].z * sc * w.z, h[i].w * sc * w.w);
    X[(size_t)token * 256 + i * 64 + lane] = o;
  }
}

// ---------- 128^2 / BK=64 GEMM core (r9-proven + T5 setprio) ---------------
// T2 swizzle both sides: linear gload_lds dest + pre-swizzled global source
// col; read XOR (frr&7)*8 (0-conflict verified r4/r5/r8/r9).
// LDS layout (shorts): As0 [0,8K) As1 [8K,16K) Bs0 [16K,24K) Bs1 [24K,32K).
// 2-phase: STAGE(t+1) issued BEFORE compute(t); one vmcnt(0)+barrier per
// K-step AFTER compute. setprio(1) around the MFMA cluster (2 blocks/CU
// give cross-block wave role diversity). Ends with __syncthreads.
DEV void gemm128d(const unsigned short* __restrict__ A,
                  const unsigned short* __restrict__ Bw, const int K,
                  const int m0, const int n0, unsigned short* LDS,
                  floatx4 (&acc)[4][4], const int tid) {
  const int lane = tid & 63;
  const int w = tid >> 6;
  const int wr = w >> 1, wc = w & 1;
  const int frr = lane & 15;
  const int frk = (lane >> 4) * 8;
  const int aswz = (frr & 7) * 8;
  const int r_a = tid >> 3;                         // 0..31
  const int c_src = ((tid & 7) ^ (r_a & 7)) * 8;    // pre-swizzled col
  const unsigned short* Ag = A + (size_t)(m0 + r_a) * K + c_src;
  const unsigned short* Bg = Bw + (size_t)(n0 + r_a) * K + c_src;
  const int NT = K >> 6;

  {
    char* AsD = (char*)LDS + tid * 16;
    char* BsD = (char*)(LDS + 16384) + tid * 16;
#pragma unroll
    for (int i = 0; i < 4; ++i) {
      gload_lds16(Ag + (size_t)i * 32 * K, AsD + i * 4096);
      gload_lds16(Bg + (size_t)i * 32 * K, BsD + i * 4096);
    }
  }
  asm volatile("s_waitcnt vmcnt(0)" ::: "memory");
  __builtin_amdgcn_s_barrier();
  FENCE();

  int cur = 0;
  for (int t = 0; t < NT; ++t) {
    if (t + 1 < NT) {
      char* AsD = (char*)(LDS + (cur ^ 1) * 8192) + tid * 16;
      char* BsD = (char*)(LDS + 16384 + (cur ^ 1) * 8192) + tid * 16;
      const int k0 = (t + 1) * 64;
#pragma unroll
      for (int i = 0; i < 4; ++i) {
        gload_lds16(Ag + (size_t)i * 32 * K + k0, AsD + i * 4096);
        gload_lds16(Bg + (size_t)i * 32 * K + k0, BsD + i * 4096);
      }
    }
    const unsigned short* Asb = LDS + cur * 8192;
    const unsigned short* Bsb = LDS + 16384 + cur * 8192;
#pragma unroll
    for (int kk = 0; kk < 2; ++kk) {
      short8 a[4], b[4];
#pragma unroll
      for (int mi = 0; mi < 4; ++mi)
        a[mi] = *(const short8*)
            &Asb[(wr * 64 + mi * 16 + frr) * 64 + ((kk * 32 + frk) ^ aswz)];
#pragma unroll
      for (int ni = 0; ni < 4; ++ni)
        b[ni] = *(const short8*)
            &Bsb[(wc * 64 + ni * 16 + frr) * 64 + ((kk * 32 + frk) ^ aswz)];
      __builtin_amdgcn_s_setprio(1);
#pragma unroll
      for (int mi = 0; mi < 4; ++mi)
#pragma unroll
        for (int ni = 0; ni < 4; ++ni)
          acc[mi][ni] = __builtin_amdgcn_mfma_f32_16x16x32_bf16(
              a[mi], b[ni], acc[mi][ni], 0, 0, 0);
      __builtin_amdgcn_s_setprio(0);
    }
    if (t + 1 < NT) {
      asm volatile("s_waitcnt vmcnt(0)" ::: "memory");
      __builtin_amdgcn_s_barrier();
      FENCE();
    }
    cur ^= 1;
  }
  __syncthreads();
}

// ---------- fused gate+o:  out = sigmoid(X@gw^T) * (Ob@ow^T), f32 ----------
// 1D grid 2048; XCD-chunked, m-major within chunk (A-tile L2-resident).
__global__ __launch_bounds__(256, 2) void k_fused_go(
    const unsigned short* __restrict__ X, const unsigned short* __restrict__ Ob,
    const unsigned short* __restrict__ gwb,
    const unsigned short* __restrict__ owb, float* __restrict__ out) {
  __shared__ unsigned short LDS[4 * 128 * 64];   // 64 KB (2 slots x A,B)
  const int tid = threadIdx.x;
  const int lane = tid & 63;
  const int w = tid >> 6;
  const int wr = w >> 1, wc = w & 1;
  const int bid = blockIdx.x;               // nwg = 2048 (multiple of 8)
  const int v = (bid & 7) * 256 + (bid >> 3);
  const int m0 = (v >> 3) * 128;            // m-major within XCD chunk
  const int n0 = (v & 7) * 128;

  floatx4 acc[4][4];
#pragma unroll
  for (int i = 0; i < 4; ++i)
#pragma unroll
    for (int j = 0; j < 4; ++j) acc[i][j] = (floatx4){0.f, 0.f, 0.f, 0.f};

  // pass 1: gate
  gemm128d(X, gwb, Hdim, m0, n0, LDS, acc, tid);

  // sigmoid -> packed bf16 stash
  unsigned pg[4][4][2];
#pragma unroll
  for (int mi = 0; mi < 4; ++mi)
#pragma unroll
    for (int ni = 0; ni < 4; ++ni) {
      float s0 = 1.0f / (1.0f + __expf(-acc[mi][ni][0]));
      float s1 = 1.0f / (1.0f + __expf(-acc[mi][ni][1]));
      float s2 = 1.0f / (1.0f + __expf(-acc[mi][ni][2]));
      float s3 = 1.0f / (1.0f + __expf(-acc[mi][ni][3]));
      pg[mi][ni][0] = pack2(s0, s1);
      pg[mi][ni][1] = pack2(s2, s3);
      acc[mi][ni] = (floatx4){0.f, 0.f, 0.f, 0.f};
    }

  // pass 2: o-proj
  gemm128d(Ob, owb, Hdim, m0, n0, LDS, acc, tid);

  // epilogue: C/D layout col = lane&15, row = (lane>>4)*4 + r
  const int rb = (lane >> 4) * 4;
#pragma unroll
  for (int mi = 0; mi < 4; ++mi)
#pragma unroll
    for (int ni = 0; ni < 4; ++ni) {
      const int n = n0 + wc * 64 + ni * 16 + (lane & 15);
#pragma unroll
      for (int r = 0; r < 4; ++r) {
        const int m = m0 + wr * 64 + mi * 16 + rb + r;
        float g = bs2f((unsigned short)(pg[mi][ni][r >> 1] >> ((r & 1) * 16)));
        out[(size_t)m * Hdim + n] = g * acc[mi][ni][r];
      }
    }
}

// ---------- fused q-path (r9-proven): q=X@qw^T -> L2-norm -> @S -> rmsnorm -
__global__ __launch_bounds__(256, 2) void k_fused_q(
    const unsigned short* __restrict__ X, const unsigned short* __restrict__ qwb,
    const unsigned short* __restrict__ St, const float* __restrict__ vnw,
    unsigned short* __restrict__ Ob) {
  __shared__ unsigned short LD[4 * 128 * 64];  // 64 KB; qt overlays [0,16K)
  const int tid = threadIdx.x;
  const int lane = tid & 63;
  const int w = tid >> 6;
  const int wr = w >> 1, wc = w & 1;
  const int bid = blockIdx.x;               // nwg = 1024
  const int v = (bid & 7) * 128 + (bid >> 3);
  const int m0 = (v >> 2) * 128;
  const int n0 = (v & 3) * 128;             // q-dim base; heads h0..h0+3
  const int h0 = n0 >> 5;
  const int batch = m0 >> 13;               // 8192 tokens per batch

  floatx4 acc[4][4];
#pragma unroll
  for (int i = 0; i < 4; ++i)
#pragma unroll
    for (int j = 0; j < 4; ++j) acc[i][j] = (floatx4){0.f, 0.f, 0.f, 0.f};

  gemm128d(X, qwb, Hdim, m0, n0, LD, acc, tid);

  const int rb = (lane >> 4) * 4;
  const int frr = lane & 15;
#pragma unroll
  for (int mi = 0; mi < 4; ++mi)
#pragma unroll
    for (int p = 0; p < 2; ++p) {
#pragma unroll
      for (int r = 0; r < 4; ++r) {
        float v0 = acc[mi][2 * p][r], v1 = acc[mi][2 * p + 1][r];
        float ss = v0 * v0 + v1 * v1;
        ss += __shfl_xor(ss, 1, 64);
        ss += __shfl_xor(ss, 2, 64);
        ss += __shfl_xor(ss, 4, 64);
        ss += __shfl_xor(ss, 8, 64);
        const float inv = 1.0f / fmaxf(sqrtf(ss), 1e-12f);
        const int m = wr * 64 + mi * 16 + rb + r;
        const int c0 = wc * 64 + p * 32 + frr;
        const int sw = (m & 7) * 8;
        LD[m * 128 + (c0 ^ sw)] = f2bs(v0 * inv);
        LD[m * 128 + ((c0 + 16) ^ sw)] = f2bs(v1 * inv);
      }
    }
  __syncthreads();

  const int frk = (lane >> 4) * 8;
  float wv[4];
#pragma unroll
  for (int ni = 0; ni < 4; ++ni) wv[ni] = vnw[ni * 16 + frr];

#pragma unroll
  for (int hh = 0; hh < 4; ++hh) {
    const unsigned short* Sp = St + (size_t)(batch * NH + h0 + hh) * (HV * HK);
    short8 bfr[4];
#pragma unroll
    for (int ni = 0; ni < 4; ++ni)
      bfr[ni] = *(const short8*)&Sp[(ni * 16 + frr) * HK + frk];
    floatx4 acc2[2][4];
#pragma unroll
    for (int i = 0; i < 2; ++i)
#pragma unroll
      for (int j = 0; j < 4; ++j) acc2[i][j] = (floatx4){0.f, 0.f, 0.f, 0.f};
    short8 af[2];
#pragma unroll
    for (int mi2 = 0; mi2 < 2; ++mi2) {
      const int m = w * 32 + mi2 * 16 + frr;
      af[mi2] = *(const short8*)&LD[m * 128 + ((hh * 32 + frk) ^ ((m & 7) * 8))];
    }
#pragma unroll
    for (int mi2 = 0; mi2 < 2; ++mi2)
#pragma unroll
      for (int ni = 0; ni < 4; ++ni)
        acc2[mi2][ni] = __builtin_amdgcn_mfma_f32_16x16x32_bf16(
            af[mi2], bfr[ni], acc2[mi2][ni], 0, 0, 0);

#pragma unroll
    for (int mi2 = 0; mi2 < 2; ++mi2)
#pragma unroll
      for (int r = 0; r < 4; ++r) {
        float ss2 = 0.f;
#pragma unroll
        for (int ni = 0; ni < 4; ++ni) ss2 += acc2[mi2][ni][r] * acc2[mi2][ni][r];
        ss2 += __shfl_xor(ss2, 1, 64);
        ss2 += __shfl_xor(ss2, 2, 64);
        ss2 += __shfl_xor(ss2, 4, 64);
        ss2 += __shfl_xor(ss2, 8, 64);
        const float sc = rsqrtf(ss2 * (1.0f / HV) + 1e-5f);
        const int m = m0 + w * 32 + mi2 * 16 + rb + r;
        unsigned short* Op = Ob + (size_t)m * Hdim + (h0 + hh) * HV;
#pragma unroll
        for (int ni = 0; ni < 4; ++ni)
          Op[ni * 16 + frr] = f2bs(acc2[mi2][ni][r] * sc * wv[ni]);
      }
  }
}

extern "C" void kernel_launch(void* const* d_in, const int* in_sizes, int n_in,
                              void* d_out, int out_size, void* d_ws, size_t ws_size,
                              hipStream_t stream) {
  const float* hs = (const float*)d_in[0];
  const float* Srec = (const float*)d_in[1];
  const float* nw = (const float*)d_in[2];
  const float* qw = (const float*)d_in[3];
  const float* vnw = (const float*)d_in[4];
  const float* ow = (const float*)d_in[5];
  const float* gw = (const float*)d_in[6];

  char* ws = (char*)d_ws;
  unsigned short* X = (unsigned short*)(ws);                          // 64 MB bf16 [M,H]
  unsigned short* Ob = (unsigned short*)(ws + ((size_t)64 << 20));    // 64 MB bf16 [M,VD]
  unsigned short* qwb = (unsigned short*)(ws + ((size_t)128 << 20));  // 1 MB
  unsigned short* gwb = (unsigned short*)(ws + ((size_t)129 << 20));  // 2 MB
  unsigned short* owb = (unsigned short*)(ws + ((size_t)131 << 20));  // 2 MB
  unsigned short* Stb = (unsigned short*)(ws + ((size_t)133 << 20));  // 256 KB

  // merged prep: weights f32 -> bf16 + S^T (one launch, 3072 blocks)
  k_prep<<<3072, 256, 0, stream>>>(qw, gw, ow, Srec, (uint2v*)qwb,
                                   (uint2v*)gwb, (uint2v*)owb, Stb);

  // x = rmsnorm(hidden) -> bf16  (wave-per-token)
  k_rmsnorm<<<Mtok / 4, 256, 0, stream>>>(hs, nw, (uint2v*)X);

  // fused q path -> Ob
  k_fused_q<<<(Mtok / 128) * (KDim / 128), 256, 0, stream>>>(
      X, qwb, Stb, vnw, Ob);

  // fused gate+o -> d_out f32
  k_fused_go<<<(Mtok / 128) * (Hdim / 128), 256, 0, stream>>>(
      X, Ob, gwb, owb, (float*)d_out);
}

// Round 18
// 252.240 us; speedup vs baseline: 1.8160x; 1.0099x over previous
//
#include <hip/hip_runtime.h>
#include <hip/hip_bf16.h>
#include <stdint.h>

typedef __attribute__((ext_vector_type(8))) short short8;
typedef __attribute__((ext_vector_type(4))) float floatx4;
typedef __attribute__((ext_vector_type(2))) unsigned int uint2v;

#define DEV static __device__ __forceinline__
#define FENCE() asm volatile("" ::: "memory")

DEV unsigned short f2bs(float f) {           // f32 -> bf16 bits, RNE
  union { float f; unsigned u; } v; v.f = f;
  unsigned u = v.u;
  u += 0x7fffu + ((u >> 16) & 1u);
  return (unsigned short)(u >> 16);
}
DEV float bs2f(unsigned short s) {
  union { unsigned u; float f; } v; v.u = ((unsigned)s) << 16;
  return v.f;
}
DEV unsigned pack2(float a, float b) {
  return (unsigned)f2bs(a) | ((unsigned)f2bs(b) << 16);
}

DEV void gload_lds16(const void* g, void* l) {
  __builtin_amdgcn_global_load_lds(
      (const __attribute__((address_space(1))) void*)g,
      (__attribute__((address_space(3))) void*)l, 16, 0, 0);
}

static constexpr int Hdim = 1024;
static constexpr int KDim = 512;
static constexpr int NH = 16;
static constexpr int HK = 32;
static constexpr int HV = 64;
static constexpr int Mtok = 4 * 8192;

// ---------- merged prep: 3x weight f32->bf16 + S^T (one launch) ----------
DEV void cvt4(const float4* __restrict__ in, uint2v* __restrict__ out, int i) {
  float4 v = in[i];
  uint2v o;
  o.x = pack2(v.x, v.y);
  o.y = pack2(v.z, v.w);
  out[i] = o;
}

__global__ __launch_bounds__(256) void k_prep(
    const float* __restrict__ qw, const float* __restrict__ gw,
    const float* __restrict__ ow, const float* __restrict__ S,
    uint2v* __restrict__ qwb, uint2v* __restrict__ gwb,
    uint2v* __restrict__ owb, unsigned short* __restrict__ St) {
  int i = blockIdx.x * 256 + threadIdx.x;
  if (i < 131072) {
    cvt4((const float4*)qw, qwb, i);
    return;
  }
  i -= 131072;
  if (i < 262144) {
    cvt4((const float4*)gw, gwb, i);
    return;
  }
  i -= 262144;
  if (i < 262144) {
    cvt4((const float4*)ow, owb, i);
    return;
  }
  i -= 262144;
  // S -> S^T bf16: St[b][h][v][k] = S[b][h][k][v]
  int k = i & 31, v = (i >> 5) & 63, bh = i >> 11;
  St[i] = f2bs(S[(size_t)(bh * HK + k) * HV + v]);
}

// ---------- rmsnorm(hidden) -> X bf16 : one WAVE per token ----------
__global__ __launch_bounds__(256) void k_rmsnorm(const float* __restrict__ hs,
                                                 const float* __restrict__ nw,
                                                 uint2v* __restrict__ X) {
  const int lane = threadIdx.x & 63;
  const int token = blockIdx.x * 4 + (threadIdx.x >> 6);
  const float4* hp = (const float4*)(hs + (size_t)token * Hdim);
  float4 h[4];
  float ss = 0.f;
#pragma unroll
  for (int i = 0; i < 4; ++i) {
    h[i] = hp[i * 64 + lane];
    ss += h[i].x * h[i].x + h[i].y * h[i].y + h[i].z * h[i].z +
          h[i].w * h[i].w;
  }
#pragma unroll
  for (int off = 1; off < 64; off <<= 1) ss += __shfl_xor(ss, off, 64);
  const float sc = rsqrtf(ss * (1.0f / Hdim) + 1e-5f);
#pragma unroll
  for (int i = 0; i < 4; ++i) {
    float4 w = ((const float4*)nw)[i * 64 + lane];
    uint2v o;
    o.x = pack2(h[i].x * sc * w.x, h[i].y * sc * w.y);
    o.y = pack2(h[i].z * sc * w.z, h[i].w * sc * w.w);
    X[(size_t)token * 256 + i * 64 + lane] = o;
  }
}

// ---------- 128^2 / BK=64 GEMM core (r9-proven; setprio removed r18) -------
// T2 swizzle both sides: linear gload_lds dest + pre-swizzled global source
// col; read XOR (frr&7)*8 (0-conflict verified r4/r5/r8/r9).
// LDS layout (shorts): As0 [0,8K) As1 [8K,16K) Bs0 [16K,24K) Bs1 [24K,32K).
// 2-phase: STAGE(t+1) issued BEFORE compute(t); one vmcnt(0)+barrier per
// K-step AFTER compute. NO setprio: r17 measured it -5us on this lockstep
// structure (m190 regime gate confirmed). Ends with __syncthreads.
DEV void gemm128d(const unsigned short* __restrict__ A,
                  const unsigned short* __restrict__ Bw, const int K,
                  const int m0, const int n0, unsigned short* LDS,
                  floatx4 (&acc)[4][4], const int tid) {
  const int lane = tid & 63;
  const int w = tid >> 6;
  const int wr = w >> 1, wc = w & 1;
  const int frr = lane & 15;
  const int frk = (lane >> 4) * 8;
  const int aswz = (frr & 7) * 8;
  const int r_a = tid >> 3;                         // 0..31
  const int c_src = ((tid & 7) ^ (r_a & 7)) * 8;    // pre-swizzled col
  const unsigned short* Ag = A + (size_t)(m0 + r_a) * K + c_src;
  const unsigned short* Bg = Bw + (size_t)(n0 + r_a) * K + c_src;
  const int NT = K >> 6;

  {
    char* AsD = (char*)LDS + tid * 16;
    char* BsD = (char*)(LDS + 16384) + tid * 16;
#pragma unroll
    for (int i = 0; i < 4; ++i) {
      gload_lds16(Ag + (size_t)i * 32 * K, AsD + i * 4096);
      gload_lds16(Bg + (size_t)i * 32 * K, BsD + i * 4096);
    }
  }
  asm volatile("s_waitcnt vmcnt(0)" ::: "memory");
  __builtin_amdgcn_s_barrier();
  FENCE();

  int cur = 0;
  for (int t = 0; t < NT; ++t) {
    if (t + 1 < NT) {
      char* AsD = (char*)(LDS + (cur ^ 1) * 8192) + tid * 16;
      char* BsD = (char*)(LDS + 16384 + (cur ^ 1) * 8192) + tid * 16;
      const int k0 = (t + 1) * 64;
#pragma unroll
      for (int i = 0; i < 4; ++i) {
        gload_lds16(Ag + (size_t)i * 32 * K + k0, AsD + i * 4096);
        gload_lds16(Bg + (size_t)i * 32 * K + k0, BsD + i * 4096);
      }
    }
    const unsigned short* Asb = LDS + cur * 8192;
    const unsigned short* Bsb = LDS + 16384 + cur * 8192;
#pragma unroll
    for (int kk = 0; kk < 2; ++kk) {
      short8 a[4], b[4];
#pragma unroll
      for (int mi = 0; mi < 4; ++mi)
        a[mi] = *(const short8*)
            &Asb[(wr * 64 + mi * 16 + frr) * 64 + ((kk * 32 + frk) ^ aswz)];
#pragma unroll
      for (int ni = 0; ni < 4; ++ni)
        b[ni] = *(const short8*)
            &Bsb[(wc * 64 + ni * 16 + frr) * 64 + ((kk * 32 + frk) ^ aswz)];
#pragma unroll
      for (int mi = 0; mi < 4; ++mi)
#pragma unroll
        for (int ni = 0; ni < 4; ++ni)
          acc[mi][ni] = __builtin_amdgcn_mfma_f32_16x16x32_bf16(
              a[mi], b[ni], acc[mi][ni], 0, 0, 0);
    }
    if (t + 1 < NT) {
      asm volatile("s_waitcnt vmcnt(0)" ::: "memory");
      __builtin_amdgcn_s_barrier();
      FENCE();
    }
    cur ^= 1;
  }
  __syncthreads();
}

// ---------- fused gate+o:  out = sigmoid(X@gw^T) * (Ob@ow^T), f32 ----------
// 1D grid 2048; XCD-chunked, m-major within chunk (A-tile L2-resident).
__global__ __launch_bounds__(256, 2) void k_fused_go(
    const unsigned short* __restrict__ X, const unsigned short* __restrict__ Ob,
    const unsigned short* __restrict__ gwb,
    const unsigned short* __restrict__ owb, float* __restrict__ out) {
  __shared__ unsigned short LDS[4 * 128 * 64];   // 64 KB (2 slots x A,B)
  const int tid = threadIdx.x;
  const int lane = tid & 63;
  const int w = tid >> 6;
  const int wr = w >> 1, wc = w & 1;
  const int bid = blockIdx.x;               // nwg = 2048 (multiple of 8)
  const int v = (bid & 7) * 256 + (bid >> 3);
  const int m0 = (v >> 3) * 128;            // m-major within XCD chunk
  const int n0 = (v & 7) * 128;

  floatx4 acc[4][4];
#pragma unroll
  for (int i = 0; i < 4; ++i)
#pragma unroll
    for (int j = 0; j < 4; ++j) acc[i][j] = (floatx4){0.f, 0.f, 0.f, 0.f};

  // pass 1: gate
  gemm128d(X, gwb, Hdim, m0, n0, LDS, acc, tid);

  // sigmoid -> packed bf16 stash
  unsigned pg[4][4][2];
#pragma unroll
  for (int mi = 0; mi < 4; ++mi)
#pragma unroll
    for (int ni = 0; ni < 4; ++ni) {
      float s0 = 1.0f / (1.0f + __expf(-acc[mi][ni][0]));
      float s1 = 1.0f / (1.0f + __expf(-acc[mi][ni][1]));
      float s2 = 1.0f / (1.0f + __expf(-acc[mi][ni][2]));
      float s3 = 1.0f / (1.0f + __expf(-acc[mi][ni][3]));
      pg[mi][ni][0] = pack2(s0, s1);
      pg[mi][ni][1] = pack2(s2, s3);
      acc[mi][ni] = (floatx4){0.f, 0.f, 0.f, 0.f};
    }

  // pass 2: o-proj
  gemm128d(Ob, owb, Hdim, m0, n0, LDS, acc, tid);

  // epilogue: C/D layout col = lane&15, row = (lane>>4)*4 + r
  const int rb = (lane >> 4) * 4;
#pragma unroll
  for (int mi = 0; mi < 4; ++mi)
#pragma unroll
    for (int ni = 0; ni < 4; ++ni) {
      const int n = n0 + wc * 64 + ni * 16 + (lane & 15);
#pragma unroll
      for (int r = 0; r < 4; ++r) {
        const int m = m0 + wr * 64 + mi * 16 + rb + r;
        float g = bs2f((unsigned short)(pg[mi][ni][r >> 1] >> ((r & 1) * 16)));
        out[(size_t)m * Hdim + n] = g * acc[mi][ni][r];
      }
    }
}

// ---------- fused q-path (r9-proven): q=X@qw^T -> L2-norm -> @S -> rmsnorm -
__global__ __launch_bounds__(256, 2) void k_fused_q(
    const unsigned short* __restrict__ X, const unsigned short* __restrict__ qwb,
    const unsigned short* __restrict__ St, const float* __restrict__ vnw,
    unsigned short* __restrict__ Ob) {
  __shared__ unsigned short LD[4 * 128 * 64];  // 64 KB; qt overlays [0,16K)
  const int tid = threadIdx.x;
  const int lane = tid & 63;
  const int w = tid >> 6;
  const int wr = w >> 1, wc = w & 1;
  const int bid = blockIdx.x;               // nwg = 1024
  const int v = (bid & 7) * 128 + (bid >> 3);
  const int m0 = (v >> 2) * 128;
  const int n0 = (v & 3) * 128;             // q-dim base; heads h0..h0+3
  const int h0 = n0 >> 5;
  const int batch = m0 >> 13;               // 8192 tokens per batch

  floatx4 acc[4][4];
#pragma unroll
  for (int i = 0; i < 4; ++i)
#pragma unroll
    for (int j = 0; j < 4; ++j) acc[i][j] = (floatx4){0.f, 0.f, 0.f, 0.f};

  gemm128d(X, qwb, Hdim, m0, n0, LD, acc, tid);

  const int rb = (lane >> 4) * 4;
  const int frr = lane & 15;
#pragma unroll
  for (int mi = 0; mi < 4; ++mi)
#pragma unroll
    for (int p = 0; p < 2; ++p) {
#pragma unroll
      for (int r = 0; r < 4; ++r) {
        float v0 = acc[mi][2 * p][r], v1 = acc[mi][2 * p + 1][r];
        float ss = v0 * v0 + v1 * v1;
        ss += __shfl_xor(ss, 1, 64);
        ss += __shfl_xor(ss, 2, 64);
        ss += __shfl_xor(ss, 4, 64);
        ss += __shfl_xor(ss, 8, 64);
        const float inv = 1.0f / fmaxf(sqrtf(ss), 1e-12f);
        const int m = wr * 64 + mi * 16 + rb + r;
        const int c0 = wc * 64 + p * 32 + frr;
        const int sw = (m & 7) * 8;
        LD[m * 128 + (c0 ^ sw)] = f2bs(v0 * inv);
        LD[m * 128 + ((c0 + 16) ^ sw)] = f2bs(v1 * inv);
      }
    }
  __syncthreads();

  const int frk = (lane >> 4) * 8;
  float wv[4];
#pragma unroll
  for (int ni = 0; ni < 4; ++ni) wv[ni] = vnw[ni * 16 + frr];

#pragma unroll
  for (int hh = 0; hh < 4; ++hh) {
    const unsigned short* Sp = St + (size_t)(batch * NH + h0 + hh) * (HV * HK);
    short8 bfr[4];
#pragma unroll
    for (int ni = 0; ni < 4; ++ni)
      bfr[ni] = *(const short8*)&Sp[(ni * 16 + frr) * HK + frk];
    floatx4 acc2[2][4];
#pragma unroll
    for (int i = 0; i < 2; ++i)
#pragma unroll
      for (int j = 0; j < 4; ++j) acc2[i][j] = (floatx4){0.f, 0.f, 0.f, 0.f};
    short8 af[2];
#pragma unroll
    for (int mi2 = 0; mi2 < 2; ++mi2) {
      const int m = w * 32 + mi2 * 16 + frr;
      af[mi2] = *(const short8*)&LD[m * 128 + ((hh * 32 + frk) ^ ((m & 7) * 8))];
    }
#pragma unroll
    for (int mi2 = 0; mi2 < 2; ++mi2)
#pragma unroll
      for (int ni = 0; ni < 4; ++ni)
        acc2[mi2][ni] = __builtin_amdgcn_mfma_f32_16x16x32_bf16(
            af[mi2], bfr[ni], acc2[mi2][ni], 0, 0, 0);

#pragma unroll
    for (int mi2 = 0; mi2 < 2; ++mi2)
#pragma unroll
      for (int r = 0; r < 4; ++r) {
        float ss2 = 0.f;
#pragma unroll
        for (int ni = 0; ni < 4; ++ni) ss2 += acc2[mi2][ni][r] * acc2[mi2][ni][r];
        ss2 += __shfl_xor(ss2, 1, 64);
        ss2 += __shfl_xor(ss2, 2, 64);
        ss2 += __shfl_xor(ss2, 4, 64);
        ss2 += __shfl_xor(ss2, 8, 64);
        const float sc = rsqrtf(ss2 * (1.0f / HV) + 1e-5f);
        const int m = m0 + w * 32 + mi2 * 16 + rb + r;
        unsigned short* Op = Ob + (size_t)m * Hdim + (h0 + hh) * HV;
#pragma unroll
        for (int ni = 0; ni < 4; ++ni)
          Op[ni * 16 + frr] = f2bs(acc2[mi2][ni][r] * sc * wv[ni]);
      }
  }
}

extern "C" void kernel_launch(void* const* d_in, const int* in_sizes, int n_in,
                              void* d_out, int out_size, void* d_ws, size_t ws_size,
                              hipStream_t stream) {
  const float* hs = (const float*)d_in[0];
  const float* Srec = (const float*)d_in[1];
  const float* nw = (const float*)d_in[2];
  const float* qw = (const float*)d_in[3];
  const float* vnw = (const float*)d_in[4];
  const float* ow = (const float*)d_in[5];
  const float* gw = (const float*)d_in[6];

  char* ws = (char*)d_ws;
  unsigned short* X = (unsigned short*)(ws);                          // 64 MB bf16 [M,H]
  unsigned short* Ob = (unsigned short*)(ws + ((size_t)64 << 20));    // 64 MB bf16 [M,VD]
  unsigned short* qwb = (unsigned short*)(ws + ((size_t)128 << 20));  // 1 MB
  unsigned short* gwb = (unsigned short*)(ws + ((size_t)129 << 20));  // 2 MB
  unsigned short* owb = (unsigned short*)(ws + ((size_t)131 << 20));  // 2 MB
  unsigned short* Stb = (unsigned short*)(ws + ((size_t)133 << 20));  // 256 KB

  // merged prep: weights f32 -> bf16 + S^T (one launch, 3072 blocks)
  k_prep<<<3072, 256, 0, stream>>>(qw, gw, ow, Srec, (uint2v*)qwb,
                                   (uint2v*)gwb, (uint2v*)owb, Stb);

  // x = rmsnorm(hidden) -> bf16  (wave-per-token)
  k_rmsnorm<<<Mtok / 4, 256, 0, stream>>>(hs, nw, (uint2v*)X);

  // fused q path -> Ob
  k_fused_q<<<(Mtok / 128) * (KDim / 128), 256, 0, stream>>>(
      X, qwb, Stb, vnw, Ob);

  // fused gate+o -> d_out f32
  k_fused_go<<<(Mtok / 128) * (Hdim / 128), 256, 0, stream>>>(
      X, Ob, gwb, owb, (float*)d_out);
}